// Round 6
// baseline (1839.421 us; speedup 1.0000x reference)
//
#include <hip/hip_runtime.h>
#include <math.h>

#define NEG_SLOPE 0.2f

typedef __attribute__((ext_vector_type(8))) short bf16x8;   // 8 bf16 (4 VGPRs)
typedef __attribute__((ext_vector_type(4))) short bf16x4;   // 8 bytes
typedef __attribute__((ext_vector_type(4))) float f32x4;    // MFMA acc

__device__ __forceinline__ float b2f(short s) {
  return __uint_as_float(((unsigned int)(unsigned short)s) << 16);
}
__device__ __forceinline__ unsigned short f2b_rne(float f) {
  unsigned int u = __float_as_uint(f);
  u = (u + 0x7FFF + ((u >> 16) & 1)) >> 16;
  return (unsigned short)u;
}

// ---------------- fp32 -> bf16 elementwise ----------------
__global__ void cvt_f2b(const float* __restrict__ in, unsigned short* __restrict__ out, size_t n)
{
  size_t i = (size_t)blockIdx.x * 256 + threadIdx.x;
  size_t stride = (size_t)gridDim.x * 256;
  for (; i < n; i += stride) out[i] = f2b_rne(in[i]);
}

// ---------------- W [K,N] f32 -> WT [N,K] bf16 ----------------
__global__ void transpose_f2b(const float* __restrict__ W, unsigned short* __restrict__ WT,
                              int K, int N)
{
  int idx = blockIdx.x * 256 + threadIdx.x;
  if (idx < K * N) {
    int k = idx / N, n = idx - k * N;
    WT[(size_t)n * K + k] = f2b_rne(W[idx]);
  }
}

// ---------------- MFMA GEMM + fused e_src/e_dst epilogue ----------------
// A bf16 [M,K] row-major, BT bf16 [N,K] row-major. BM=BN=128, BK=32, 4 waves.
// EMODE = channels-per-head (64 or 128). Head boundaries align with wave (64)
// or block (128) col spans, so e-dots need no atomics.
template<int EMODE>
__global__ __launch_bounds__(256) void gemm_mfma(
    const unsigned short* __restrict__ A, const unsigned short* __restrict__ BT,
    unsigned short* __restrict__ Cout, int M, int N, int K,
    const float* __restrict__ a_src, const float* __restrict__ a_dst,
    float* __restrict__ es, float* __restrict__ ed, int nh)
{
  const int LDT = 40;
  __shared__ unsigned short As[128 * 40];
  __shared__ unsigned short Bs[128 * 40];
  const int tid  = threadIdx.x;
  const int wave = tid >> 6;
  const int lane = tid & 63;
  const int ln   = lane & 15;
  const int quad = lane >> 4;
  const int wr0  = (wave >> 1) * 64;
  const int wc0  = (wave & 1) * 64;
  const int bm   = blockIdx.y * 128;
  const int bn   = blockIdx.x * 128;
  const int srow  = tid >> 2;
  const int skoff = (tid & 3) * 8;

  f32x4 acc[4][4];
  const f32x4 z4 = {0.f, 0.f, 0.f, 0.f};
#pragma unroll
  for (int i = 0; i < 4; ++i)
#pragma unroll
    for (int j = 0; j < 4; ++j) acc[i][j] = z4;

  for (int k0 = 0; k0 < K; k0 += 32) {
#pragma unroll
    for (int p = 0; p < 2; ++p) {
      int r = srow + p * 64;
      bf16x8 va = {0, 0, 0, 0, 0, 0, 0, 0};
      if (bm + r < M)
        va = *(const bf16x8*)(A + (size_t)(bm + r) * K + k0 + skoff);
      *(bf16x8*)(&As[r * LDT + skoff]) = va;
      bf16x8 vb = *(const bf16x8*)(BT + (size_t)(bn + r) * K + k0 + skoff);
      *(bf16x8*)(&Bs[r * LDT + skoff]) = vb;
    }
    __syncthreads();
    bf16x8 af[4], bfv[4];
#pragma unroll
    for (int i = 0; i < 4; ++i)
      af[i] = *(const bf16x8*)(&As[(wr0 + i * 16 + ln) * LDT + quad * 8]);
#pragma unroll
    for (int j = 0; j < 4; ++j)
      bfv[j] = *(const bf16x8*)(&Bs[(wc0 + j * 16 + ln) * LDT + quad * 8]);
#pragma unroll
    for (int i = 0; i < 4; ++i)
#pragma unroll
      for (int j = 0; j < 4; ++j)
        acc[i][j] = __builtin_amdgcn_mfma_f32_16x16x32_bf16(af[i], bfv[j], acc[i][j], 0, 0, 0);
    __syncthreads();
  }

  // ---- C store (bf16) ----
#pragma unroll
  for (int i = 0; i < 4; ++i) {
#pragma unroll
    for (int r = 0; r < 4; ++r) {
      int row = bm + wr0 + i * 16 + quad * 4 + r;
      if (row >= M) continue;
#pragma unroll
      for (int j = 0; j < 4; ++j) {
        int col = bn + wc0 + j * 16 + ln;
        Cout[(size_t)row * N + col] = f2b_rne(acc[i][j][r]);
      }
    }
  }

  // ---- fused e_src/e_dst: per-row dot over this wave's 64 cols ----
  float asv[4], adv[4];
#pragma unroll
  for (int j = 0; j < 4; ++j) {
    int col = bn + wc0 + j * 16 + ln;
    asv[j] = a_src[col];
    adv[j] = a_dst[col];
  }
  if (EMODE == 64) {
    const int head = (bn + wc0) >> 6;
#pragma unroll
    for (int i = 0; i < 4; ++i) {
#pragma unroll
      for (int r = 0; r < 4; ++r) {
        float ps = 0.f, pd = 0.f;
#pragma unroll
        for (int j = 0; j < 4; ++j) {
          ps = fmaf(acc[i][j][r], asv[j], ps);
          pd = fmaf(acc[i][j][r], adv[j], pd);
        }
        for (int off = 8; off; off >>= 1) {
          ps += __shfl_down(ps, off, 16);
          pd += __shfl_down(pd, off, 16);
        }
        if (ln == 0) {
          int row = bm + wr0 + i * 16 + quad * 4 + r;
          if (row < M) {
            es[(size_t)row * nh + head] = ps;
            ed[(size_t)row * nh + head] = pd;
          }
        }
      }
    }
  } else {  // EMODE == 128: block = exactly one head; combine the 2 col-halves via LDS
    float* esp = (float*)As;          // [128][2]
    float* edp = esp + 256;
#pragma unroll
    for (int i = 0; i < 4; ++i) {
#pragma unroll
      for (int r = 0; r < 4; ++r) {
        float ps = 0.f, pd = 0.f;
#pragma unroll
        for (int j = 0; j < 4; ++j) {
          ps = fmaf(acc[i][j][r], asv[j], ps);
          pd = fmaf(acc[i][j][r], adv[j], pd);
        }
        for (int off = 8; off; off >>= 1) {
          ps += __shfl_down(ps, off, 16);
          pd += __shfl_down(pd, off, 16);
        }
        if (ln == 0) {
          int rl = wr0 + i * 16 + quad * 4 + r;
          esp[rl * 2 + (wc0 >> 6)] = ps;
          edp[rl * 2 + (wc0 >> 6)] = pd;
        }
      }
    }
    __syncthreads();
    if (tid < 128) {
      int row = bm + tid;
      if (row < M) {
        int head = bn >> 7;
        es[(size_t)row * nh + head] = esp[tid * 2] + esp[tid * 2 + 1];
        ed[(size_t)row * nh + head] = edp[tid * 2] + edp[tid * 2 + 1];
      }
    }
  }
}

// ---------------- skinny MFMA GEMM, N=64, split-K, fp32 partials ----------------
__global__ __launch_bounds__(256) void gemm_mfma_n64(
    const unsigned short* __restrict__ A, int lda,
    const unsigned short* __restrict__ BT, int ldb,
    float* __restrict__ Cp, int M, int kchunk)
{
  const int LDT = 72;
  __shared__ unsigned short As[128 * 72];
  __shared__ unsigned short Bs[64 * 72];
  const int tid  = threadIdx.x;
  const int wave = tid >> 6;
  const int lane = tid & 63;
  const int ln   = lane & 15;
  const int quad = lane >> 4;
  const int ks   = blockIdx.x;
  const int bm   = blockIdx.y * 128;
  const int k_beg = ks * kchunk;
  const int k_end = k_beg + kchunk;
  const int arow = tid >> 1;
  const int akb  = (tid & 1) * 32;
  const int brow = tid >> 2;
  const int bkb  = (tid & 3) * 16;

  f32x4 acc[2][4];
  const f32x4 z4 = {0.f, 0.f, 0.f, 0.f};
#pragma unroll
  for (int i = 0; i < 2; ++i)
#pragma unroll
    for (int j = 0; j < 4; ++j) acc[i][j] = z4;

  for (int k0 = k_beg; k0 < k_end; k0 += 64) {
    const unsigned short* ap = A + (size_t)(bm + arow) * lda + k0 + akb;
#pragma unroll
    for (int q = 0; q < 4; ++q)
      *(bf16x8*)(&As[arow * LDT + akb + q * 8]) = *(const bf16x8*)(ap + q * 8);
    const unsigned short* bp = BT + (size_t)brow * ldb + k0 + bkb;
#pragma unroll
    for (int q = 0; q < 2; ++q)
      *(bf16x8*)(&Bs[brow * LDT + bkb + q * 8]) = *(const bf16x8*)(bp + q * 8);
    __syncthreads();
#pragma unroll
    for (int kk = 0; kk < 2; ++kk) {
      bf16x8 af[2], bfv[4];
#pragma unroll
      for (int i = 0; i < 2; ++i)
        af[i] = *(const bf16x8*)(&As[(wave * 32 + i * 16 + ln) * LDT + kk * 32 + quad * 8]);
#pragma unroll
      for (int j = 0; j < 4; ++j)
        bfv[j] = *(const bf16x8*)(&Bs[(j * 16 + ln) * LDT + kk * 32 + quad * 8]);
#pragma unroll
      for (int i = 0; i < 2; ++i)
#pragma unroll
        for (int j = 0; j < 4; ++j)
          acc[i][j] = __builtin_amdgcn_mfma_f32_16x16x32_bf16(af[i], bfv[j], acc[i][j], 0, 0, 0);
    }
    __syncthreads();
  }
#pragma unroll
  for (int i = 0; i < 2; ++i)
#pragma unroll
    for (int r = 0; r < 4; ++r) {
      int row = bm + wave * 32 + i * 16 + quad * 4 + r;
#pragma unroll
      for (int j = 0; j < 4; ++j)
        Cp[((size_t)ks * M + row) * 64 + j * 16 + ln] = acc[i][j][r];
    }
}

// ---------------- fp partial reduce + bias -> bf16 into z cols [512,576) ----------------
__global__ void fp_finish(const float* __restrict__ Cp, int ksplit, int M,
                          const float* __restrict__ bfp,
                          unsigned short* __restrict__ zb)
{
  const int g = blockIdx.x;
  const int j = threadIdx.x;
  float s = bfp[j];
  for (int ks = 0; ks < ksplit; ++ks) s += Cp[((size_t)ks * M + g) * 64 + j];
  zb[(size_t)g * 576 + 512 + j] = f2b_rne(s);
}

// ---------------- mlp partial reduce + bias + relu + fc2 dot -> out ----------------
__global__ void mlp_finish(const float* __restrict__ Cp, int ksplit, int M,
                           const float* __restrict__ bfc1,
                           const float* __restrict__ Wfc2, const float* __restrict__ bfc2,
                           float* __restrict__ out)
{
  const int g = blockIdx.x;
  const int j = threadIdx.x;
  float s = bfc1[j];
  for (int ks = 0; ks < ksplit; ++ks) s += Cp[((size_t)ks * M + g) * 64 + j];
  s = s > 0.f ? s : 0.f;
  float term = s * Wfc2[j];
  for (int off = 32; off; off >>= 1) term += __shfl_down(term, off, 64);
  if (j == 0) out[g] = term + bfc2[0];
}

// ---------------- CSR build ----------------
__global__ void count_deg(const int* __restrict__ ei, int E, int* __restrict__ deg)
{
  int e = blockIdx.x * 256 + threadIdx.x;
  if (e < E) atomicAdd(&deg[ei[E + e]], 1);
}

__global__ void fill_csr(const int* __restrict__ ei, int E, int* __restrict__ cursor,
                         const int* __restrict__ rowptr, int* __restrict__ csr_src)
{
  int e = blockIdx.x * 256 + threadIdx.x;
  if (e < E) {
    int d = ei[E + e];
    int pos = atomicAdd(&cursor[d], 1);
    csr_src[rowptr[d] + pos] = ei[e];
  }
}

__global__ void count_graph(const int* __restrict__ batch, int N, int* __restrict__ gcnt)
{
  int i = blockIdx.x * 256 + threadIdx.x;
  if (i < N) atomicAdd(&gcnt[batch[i]], 1);
}

__global__ void inv_counts(const int* __restrict__ gcnt, float* __restrict__ cinv, int G)
{
  int g = blockIdx.x * 256 + threadIdx.x;
  if (g < G) cinv[g] = 1.0f / (float)max(gcnt[g], 1);
}

// ---------------- 3-phase exclusive scan ----------------
__global__ void scan_p1(const int* __restrict__ vals, int n, int* __restrict__ bsum)
{
  __shared__ int red[256];
  int base = blockIdx.x * 1024;
  int t = threadIdx.x;
  int s = 0;
#pragma unroll
  for (int i = 0; i < 4; ++i) {
    int idx = base + i * 256 + t;
    if (idx < n) s += vals[idx];
  }
  red[t] = s;
  __syncthreads();
  for (int off = 128; off; off >>= 1) {
    if (t < off) red[t] += red[t + off];
    __syncthreads();
  }
  if (t == 0) bsum[blockIdx.x] = red[0];
}

__global__ void scan_p2(const int* __restrict__ bsum, int* __restrict__ bpre,
                        int nb, int* __restrict__ rowptr, int n)
{
  __shared__ int tmp[128];
  int t = threadIdx.x;
  int v = (t < nb) ? bsum[t] : 0;
  tmp[t] = v;
  __syncthreads();
  for (int off = 1; off < 128; off <<= 1) {
    int add = (t >= off) ? tmp[t - off] : 0;
    __syncthreads();
    tmp[t] += add;
    __syncthreads();
  }
  if (t < nb) bpre[t] = tmp[t] - v;
  if (t == 127) rowptr[n] = tmp[127];
}

__global__ void scan_p3(const int* __restrict__ vals, const int* __restrict__ bpre,
                        int n, int* __restrict__ rowptr)
{
  __shared__ int tmp[256];
  int t = threadIdx.x;
  int base = blockIdx.x * 1024 + t * 4;
  int v[4]; int s = 0;
#pragma unroll
  for (int i = 0; i < 4; ++i) {
    int idx = base + i;
    v[i] = (idx < n) ? vals[idx] : 0;
    s += v[i];
  }
  tmp[t] = s;
  __syncthreads();
  for (int off = 1; off < 256; off <<= 1) {
    int add = (t >= off) ? tmp[t - off] : 0;
    __syncthreads();
    tmp[t] += add;
    __syncthreads();
  }
  int run = bpre[blockIdx.x] + tmp[t] - s;
#pragma unroll
  for (int i = 0; i < 4; ++i) {
    int idx = base + i;
    if (idx < n) rowptr[idx] = run;
    run += v[i];
  }
}

// ---------------- normalized attention weights ----------------
__global__ void alpha_kernel(const float* __restrict__ es, const float* __restrict__ ed,
                             const int* __restrict__ rowptr, const int* __restrict__ csr_src,
                             float* __restrict__ w_csr, float* __restrict__ wself,
                             int N, int nh)
{
  int idx = blockIdx.x * 256 + threadIdx.x;
  if (idx >= N * nh) return;
  const int dst = idx / nh;
  const int h = idx - dst * nh;
  const float edh = ed[(size_t)dst * nh + h];
  const int beg = rowptr[dst], end = rowptr[dst + 1];
  float sum = 0.f;
  for (int e = beg; e < end; ++e) {
    int s = csr_src[e];
    float l = es[(size_t)s * nh + h] + edh;
    l = l >= 0.f ? l : NEG_SLOPE * l;
    float w = expf(l);
    w_csr[(size_t)e * nh + h] = w;
    sum += w;
  }
  float ls = es[(size_t)dst * nh + h] + edh;
  ls = ls >= 0.f ? ls : NEG_SLOPE * ls;
  float wsl = expf(ls);
  sum += wsl;
  const float inv = 1.0f / sum;
  for (int e = beg; e < end; ++e) w_csr[(size_t)e * nh + h] *= inv;
  wself[(size_t)dst * nh + h] = wsl * inv;
}

// ---------------- weighted gather aggregation + bias + ELU ----------------
// FUSE_POOL=0: write bf16 out[dst]. FUSE_POOL=1: atomicAdd elu(v)*cinv into pooled.
template<int FUSE_POOL>
__global__ __launch_bounds__(256) void aggregate_b(
    const unsigned short* __restrict__ h,
    const float* __restrict__ w_csr, const float* __restrict__ wself,
    const int* __restrict__ rowptr, const int* __restrict__ csr_src,
    const float* __restrict__ bias, unsigned short* __restrict__ out,
    const int* __restrict__ batch, const float* __restrict__ cinv,
    float* __restrict__ pooled, int col_off,
    int N, int nh, int C)
{
  const int HC = nh * C;
  const int CH8 = HC >> 3;
  const int dpb = 256 / CH8;
  const int grp = threadIdx.x / CH8;
  const int lane = threadIdx.x - grp * CH8;
  const int dst = blockIdx.x * dpb + grp;
  if (dst >= N) return;
  const int ch = lane << 3;
  const int head = ch / C;
  const int beg = rowptr[dst], end = rowptr[dst + 1];
  float acc[8] = {0.f, 0.f, 0.f, 0.f, 0.f, 0.f, 0.f, 0.f};
  int e = beg;
  for (; e + 1 < end; e += 2) {
    int s0 = csr_src[e], s1 = csr_src[e + 1];
    float a0 = w_csr[(size_t)e * nh + head];
    float a1 = w_csr[(size_t)(e + 1) * nh + head];
    bf16x8 h0 = *(const bf16x8*)(h + (size_t)s0 * HC + ch);
    bf16x8 h1 = *(const bf16x8*)(h + (size_t)s1 * HC + ch);
#pragma unroll
    for (int r = 0; r < 8; ++r) acc[r] = fmaf(a0, b2f(h0[r]), acc[r]);
#pragma unroll
    for (int r = 0; r < 8; ++r) acc[r] = fmaf(a1, b2f(h1[r]), acc[r]);
  }
  if (e < end) {
    int s0 = csr_src[e];
    float a0 = w_csr[(size_t)e * nh + head];
    bf16x8 h0 = *(const bf16x8*)(h + (size_t)s0 * HC + ch);
#pragma unroll
    for (int r = 0; r < 8; ++r) acc[r] = fmaf(a0, b2f(h0[r]), acc[r]);
  }
  {
    float a = wself[(size_t)dst * nh + head];
    bf16x8 hv = *(const bf16x8*)(h + (size_t)dst * HC + ch);
#pragma unroll
    for (int r = 0; r < 8; ++r) acc[r] = fmaf(a, b2f(hv[r]), acc[r]);
  }
  if (FUSE_POOL) {
    const int g = batch[dst];
    const float invc = cinv[g];
    float* pp = pooled + (size_t)g * 512 + col_off + ch;
#pragma unroll
    for (int r = 0; r < 8; ++r) {
      float v = acc[r] + bias[ch + r];
      v = v > 0.f ? v : (expf(v) - 1.0f);
      atomicAdd(&pp[r], v * invc);
    }
  } else {
    bf16x8 o;
#pragma unroll
    for (int r = 0; r < 8; ++r) {
      float v = acc[r] + bias[ch + r];
      v = v > 0.f ? v : (expf(v) - 1.0f);
      o[r] = (short)f2b_rne(v);
    }
    *(bf16x8*)(out + (size_t)dst * HC + ch) = o;
  }
}

// ---------------- pooled fp32 -> zb bf16 cols [0,512) ----------------
__global__ void pool2zb(const float* __restrict__ pooled, unsigned short* __restrict__ zb)
{
  const int g = blockIdx.x;
  const int t = threadIdx.x;
#pragma unroll
  for (int k = 0; k < 2; ++k) {
    int c = t + k * 256;
    zb[(size_t)g * 576 + c] = f2b_rne(pooled[(size_t)g * 512 + c]);
  }
}

// ---------------- launcher ----------------
extern "C" void kernel_launch(void* const* d_in, const int* in_sizes, int n_in,
                              void* d_out, int out_size, void* d_ws, size_t ws_size,
                              hipStream_t stream)
{
  const float* x      = (const float*)d_in[0];
  const int*   ei     = (const int*)d_in[1];
  const int*   batch  = (const int*)d_in[2];
  const float* fp     = (const float*)d_in[3];
  const float* W1     = (const float*)d_in[4];
  const float* a_src1 = (const float*)d_in[5];
  const float* a_dst1 = (const float*)d_in[6];
  const float* b1     = (const float*)d_in[7];
  const float* W2     = (const float*)d_in[8];
  const float* a_src2 = (const float*)d_in[9];
  const float* a_dst2 = (const float*)d_in[10];
  const float* b2     = (const float*)d_in[11];
  const float* Wfp    = (const float*)d_in[12];
  const float* bfp    = (const float*)d_in[13];
  const float* Wfc1   = (const float*)d_in[14];
  const float* bfc1   = (const float*)d_in[15];
  const float* Wfc2   = (const float*)d_in[16];
  const float* bfc2   = (const float*)d_in[17];
  float* out = (float*)d_out;

  const int NN = in_sizes[0] / 128;
  const int E  = in_sizes[1] / 2;
  const int G  = in_sizes[3] / 2048;
  const int FIN = 128, H = 4, C1 = 64, C2 = 128;
  const int HC1 = H * C1;   // 256
  const int HC2 = H * C2;   // 512
  const int KFP = in_sizes[3] / G;   // 2048
  const int KZ  = HC2 + 64;          // 576
  const int KS_FP = 16;
  const int KS_Z  = 9;

  unsigned short *xb, *h1b, *h2b, *agg1b, *W1T, *W2T;
  unsigned short *fpb, *WfpT, *Wfc1T, *zb;
  float *es1, *ed1, *wself1, *w1, *es2, *ed2, *wself2, *w2, *Cp_fp, *Cp_z;
  float *pooled, *cinv;
  int *deg, *cursor, *gcnt, *rowptr_n, *rowptr_g, *csr_src, *bsum, *bpre;

  auto build = [&](int npart) -> size_t {
    const int Cpart = HC2 / npart;
    char* base = (char*)d_ws;
    size_t off = 0;
    auto alloc = [&](size_t bytes) {
      char* p = base + off; off += (bytes + 15) & ~(size_t)15; return p;
    };
    size_t xb_sz  = ((size_t)NN * FIN * 2 + 15) & ~(size_t)15;
    size_t h1b_sz = ((size_t)NN * HC1 * 2 + 15) & ~(size_t)15;
    size_t h2b_sz = ((size_t)NN * Cpart * 2 + 15) & ~(size_t)15;
    size_t r0_sz  = xb_sz + h1b_sz; if (h2b_sz > r0_sz) r0_sz = h2b_sz;
    char* R0 = alloc(r0_sz);
    xb  = (unsigned short*)R0;
    h1b = (unsigned short*)(R0 + xb_sz);
    h2b = (unsigned short*)R0;
    agg1b  = (unsigned short*)alloc((size_t)NN * HC1 * 2);
    es1    = (float*)alloc((size_t)NN * H * 4);
    ed1    = (float*)alloc((size_t)NN * H * 4);
    wself1 = (float*)alloc((size_t)NN * H * 4);
    w1     = (float*)alloc((size_t)E * H * 4);
    es2    = (float*)alloc((size_t)NN * H * 4);
    ed2    = (float*)alloc((size_t)NN * H * 4);
    wself2 = (float*)alloc((size_t)NN * H * 4);
    w2     = (float*)alloc((size_t)E * H * 4);
    zb     = (unsigned short*)alloc((size_t)G * KZ * 2);
    fpb    = (unsigned short*)alloc((size_t)G * KFP * 2);
    WfpT   = (unsigned short*)alloc((size_t)64 * KFP * 2);
    Wfc1T  = (unsigned short*)alloc((size_t)64 * KZ * 2);
    Cp_fp  = (float*)alloc((size_t)KS_FP * G * 64 * 4);
    Cp_z   = (float*)alloc((size_t)KS_Z * G * 64 * 4);
    pooled = (float*)alloc((size_t)G * HC2 * 4);
    cinv   = (float*)alloc((size_t)G * 4);
    W1T    = (unsigned short*)alloc((size_t)HC1 * FIN * 2);
    W2T    = (unsigned short*)alloc((size_t)HC2 * HC1 * 2);
    deg      = (int*)alloc((size_t)NN * 4);
    cursor   = (int*)alloc((size_t)NN * 4);
    gcnt     = (int*)alloc((size_t)G * 4);
    rowptr_n = (int*)alloc(((size_t)NN + 1) * 4);
    rowptr_g = (int*)alloc(((size_t)G + 1) * 4);
    csr_src  = (int*)alloc((size_t)E * 4);
    bsum     = (int*)alloc(128 * 4);
    bpre     = (int*)alloc(128 * 4);
    return off;
  };
  int npart = 1;
  if (build(1) > ws_size) { npart = 2; build(2); }
  const int HP = H / npart;
  const int Cpart = HP * C2;

  // ---- conversions ----
  {
    size_t nx = (size_t)NN * FIN;
    cvt_f2b<<<(int)((nx + 255) / 256), 256, 0, stream>>>(x, xb, nx);
    size_t nf = (size_t)G * KFP;
    cvt_f2b<<<2048, 256, 0, stream>>>(fp, fpb, nf);
    transpose_f2b<<<(FIN * HC1 + 255) / 256, 256, 0, stream>>>(W1, W1T, FIN, HC1);
    transpose_f2b<<<(HC1 * HC2 + 255) / 256, 256, 0, stream>>>(W2, W2T, HC1, HC2);
    transpose_f2b<<<(KFP * 64 + 255) / 256, 256, 0, stream>>>(Wfp, WfpT, KFP, 64);
    transpose_f2b<<<(KZ * 64 + 255) / 256, 256, 0, stream>>>(Wfc1, Wfc1T, KZ, 64);
  }

  // ---- fingerprint branch ----
  {
    dim3 gg(KS_FP, G / 128);
    gemm_mfma_n64<<<gg, 256, 0, stream>>>(fpb, KFP, WfpT, KFP, Cp_fp, G, KFP / KS_FP);
    fp_finish<<<G, 64, 0, stream>>>(Cp_fp, KS_FP, G, bfp, zb);
  }

  // ---- CSR by dst + graph segment ptrs ----
  hipMemsetAsync(deg, 0, sizeof(int) * (2 * (size_t)NN + G), stream);
  hipMemsetAsync(pooled, 0, (size_t)G * HC2 * 4, stream);
  count_deg<<<(E + 255) / 256, 256, 0, stream>>>(ei, E, deg);
  {
    int nb = (NN + 1023) / 1024;
    scan_p1<<<nb, 256, 0, stream>>>(deg, NN, bsum);
    scan_p2<<<1, 128, 0, stream>>>(bsum, bpre, nb, rowptr_n, NN);
    scan_p3<<<nb, 256, 0, stream>>>(deg, bpre, NN, rowptr_n);
  }
  fill_csr<<<(E + 255) / 256, 256, 0, stream>>>(ei, E, cursor, rowptr_n, csr_src);
  count_graph<<<(NN + 255) / 256, 256, 0, stream>>>(batch, NN, gcnt);
  inv_counts<<<(G + 255) / 256, 256, 0, stream>>>(gcnt, cinv, G);
  {
    int nb = (G + 1023) / 1024;
    scan_p1<<<nb, 256, 0, stream>>>(gcnt, G, bsum);
    scan_p2<<<1, 128, 0, stream>>>(bsum, bpre, nb, rowptr_g, G);
    scan_p3<<<nb, 256, 0, stream>>>(gcnt, bpre, G, rowptr_g);
  }

  // ---- conv1: GEMM (+fused e) -> alpha -> aggregate ----
  {
    dim3 gg(HC1 / 128, (NN + 127) / 128);
    gemm_mfma<64><<<gg, 256, 0, stream>>>(xb, W1T, h1b, NN, HC1, FIN,
                                          a_src1, a_dst1, es1, ed1, H);
  }
  alpha_kernel<<<(NN * H + 255) / 256, 256, 0, stream>>>(es1, ed1, rowptr_n, csr_src,
                                                         w1, wself1, NN, H);
  aggregate_b<0><<<(NN + 7) / 8, 256, 0, stream>>>(h1b, w1, wself1, rowptr_n, csr_src,
                                                   b1, agg1b, nullptr, nullptr, nullptr, 0,
                                                   NN, H, C1);

  // ---- conv2, by partition: GEMM (+fused e) -> alpha -> aggregate (+fused pool) ----
  for (int p = 0; p < npart; ++p) {
    dim3 gg(Cpart / 128, (NN + 127) / 128);
    gemm_mfma<128><<<gg, 256, 0, stream>>>(agg1b, W2T + (size_t)p * Cpart * HC1, h2b,
                                           NN, Cpart, HC1,
                                           a_src2 + (size_t)p * Cpart,
                                           a_dst2 + (size_t)p * Cpart,
                                           es2, ed2, HP);
    alpha_kernel<<<(NN * HP + 255) / 256, 256, 0, stream>>>(es2, ed2, rowptr_n, csr_src,
                                                            w2, wself2, NN, HP);
    {
      int CH8 = Cpart >> 3;
      int dpb = 256 / CH8;
      aggregate_b<1><<<(NN + dpb - 1) / dpb, 256, 0, stream>>>(
          h2b, w2, wself2, rowptr_n, csr_src, b2 + (size_t)p * Cpart, nullptr,
          batch, cinv, pooled, p * Cpart, NN, HP, C2);
    }
  }
  pool2zb<<<G, 256, 0, stream>>>(pooled, zb);

  // ---- head ----
  {
    dim3 gg(KS_Z, G / 128);
    gemm_mfma_n64<<<gg, 256, 0, stream>>>(zb, KZ, Wfc1T, KZ, Cp_z, G, KZ / KS_Z);
    mlp_finish<<<G, 64, 0, stream>>>(Cp_z, KS_Z, G, bfc1, Wfc2, bfc2, out);
  }
}

// Round 7
// 608.557 us; speedup vs baseline: 3.0226x; 3.0226x over previous
//
#include <hip/hip_runtime.h>
#include <math.h>

#define NEG_SLOPE 0.2f

typedef __attribute__((ext_vector_type(8))) short bf16x8;   // 8 bf16 (4 VGPRs)
typedef __attribute__((ext_vector_type(4))) short bf16x4;   // 8 bytes
typedef __attribute__((ext_vector_type(4))) float f32x4;    // MFMA acc

__device__ __forceinline__ float b2f(short s) {
  return __uint_as_float(((unsigned int)(unsigned short)s) << 16);
}
__device__ __forceinline__ unsigned short f2b_rne(float f) {
  unsigned int u = __float_as_uint(f);
  u = (u + 0x7FFF + ((u >> 16) & 1)) >> 16;
  return (unsigned short)u;
}

// ---------------- fp32 -> bf16 elementwise ----------------
__global__ void cvt_f2b(const float* __restrict__ in, unsigned short* __restrict__ out, size_t n)
{
  size_t i = (size_t)blockIdx.x * 256 + threadIdx.x;
  size_t stride = (size_t)gridDim.x * 256;
  for (; i < n; i += stride) out[i] = f2b_rne(in[i]);
}

// ---------------- W [K,N] f32 -> WT [N,K] bf16 ----------------
__global__ void transpose_f2b(const float* __restrict__ W, unsigned short* __restrict__ WT,
                              int K, int N)
{
  int idx = blockIdx.x * 256 + threadIdx.x;
  if (idx < K * N) {
    int k = idx / N, n = idx - k * N;
    WT[(size_t)n * K + k] = f2b_rne(W[idx]);
  }
}

// ---------------- MFMA GEMM + fused e_src/e_dst epilogue ----------------
// A bf16 [M,K] row-major, BT bf16 [N,K] row-major. BM=BN=128, BK=32, 4 waves.
// EMODE = channels-per-head (64 or 128); head boundaries align with wave/block
// col spans so the e-dots need no atomics. (Fused-e verified good in R6.)
template<int EMODE>
__global__ __launch_bounds__(256) void gemm_mfma(
    const unsigned short* __restrict__ A, const unsigned short* __restrict__ BT,
    unsigned short* __restrict__ Cout, int M, int N, int K,
    const float* __restrict__ a_src, const float* __restrict__ a_dst,
    float* __restrict__ es, float* __restrict__ ed, int nh)
{
  const int LDT = 40;
  __shared__ unsigned short As[128 * 40];
  __shared__ unsigned short Bs[128 * 40];
  const int tid  = threadIdx.x;
  const int wave = tid >> 6;
  const int lane = tid & 63;
  const int ln   = lane & 15;
  const int quad = lane >> 4;
  const int wr0  = (wave >> 1) * 64;
  const int wc0  = (wave & 1) * 64;
  const int bm   = blockIdx.y * 128;
  const int bn   = blockIdx.x * 128;
  const int srow  = tid >> 2;
  const int skoff = (tid & 3) * 8;

  f32x4 acc[4][4];
  const f32x4 z4 = {0.f, 0.f, 0.f, 0.f};
#pragma unroll
  for (int i = 0; i < 4; ++i)
#pragma unroll
    for (int j = 0; j < 4; ++j) acc[i][j] = z4;

  for (int k0 = 0; k0 < K; k0 += 32) {
#pragma unroll
    for (int p = 0; p < 2; ++p) {
      int r = srow + p * 64;
      bf16x8 va = {0, 0, 0, 0, 0, 0, 0, 0};
      if (bm + r < M)
        va = *(const bf16x8*)(A + (size_t)(bm + r) * K + k0 + skoff);
      *(bf16x8*)(&As[r * LDT + skoff]) = va;
      bf16x8 vb = *(const bf16x8*)(BT + (size_t)(bn + r) * K + k0 + skoff);
      *(bf16x8*)(&Bs[r * LDT + skoff]) = vb;
    }
    __syncthreads();
    bf16x8 af[4], bfv[4];
#pragma unroll
    for (int i = 0; i < 4; ++i)
      af[i] = *(const bf16x8*)(&As[(wr0 + i * 16 + ln) * LDT + quad * 8]);
#pragma unroll
    for (int j = 0; j < 4; ++j)
      bfv[j] = *(const bf16x8*)(&Bs[(wc0 + j * 16 + ln) * LDT + quad * 8]);
#pragma unroll
    for (int i = 0; i < 4; ++i)
#pragma unroll
      for (int j = 0; j < 4; ++j)
        acc[i][j] = __builtin_amdgcn_mfma_f32_16x16x32_bf16(af[i], bfv[j], acc[i][j], 0, 0, 0);
    __syncthreads();
  }

  // ---- C store (bf16) ----
#pragma unroll
  for (int i = 0; i < 4; ++i) {
#pragma unroll
    for (int r = 0; r < 4; ++r) {
      int row = bm + wr0 + i * 16 + quad * 4 + r;
      if (row >= M) continue;
#pragma unroll
      for (int j = 0; j < 4; ++j) {
        int col = bn + wc0 + j * 16 + ln;
        Cout[(size_t)row * N + col] = f2b_rne(acc[i][j][r]);
      }
    }
  }

  // ---- fused e_src/e_dst ----
  float asv[4], adv[4];
#pragma unroll
  for (int j = 0; j < 4; ++j) {
    int col = bn + wc0 + j * 16 + ln;
    asv[j] = a_src[col];
    adv[j] = a_dst[col];
  }
  if (EMODE == 64) {
    const int head = (bn + wc0) >> 6;
#pragma unroll
    for (int i = 0; i < 4; ++i) {
#pragma unroll
      for (int r = 0; r < 4; ++r) {
        float ps = 0.f, pd = 0.f;
#pragma unroll
        for (int j = 0; j < 4; ++j) {
          ps = fmaf(acc[i][j][r], asv[j], ps);
          pd = fmaf(acc[i][j][r], adv[j], pd);
        }
        for (int off = 8; off; off >>= 1) {
          ps += __shfl_down(ps, off, 16);
          pd += __shfl_down(pd, off, 16);
        }
        if (ln == 0) {
          int row = bm + wr0 + i * 16 + quad * 4 + r;
          if (row < M) {
            es[(size_t)row * nh + head] = ps;
            ed[(size_t)row * nh + head] = pd;
          }
        }
      }
    }
  } else {  // EMODE == 128: block = one head; combine col-halves via LDS
    float* esp = (float*)As;          // [128][2]
    float* edp = esp + 256;
#pragma unroll
    for (int i = 0; i < 4; ++i) {
#pragma unroll
      for (int r = 0; r < 4; ++r) {
        float ps = 0.f, pd = 0.f;
#pragma unroll
        for (int j = 0; j < 4; ++j) {
          ps = fmaf(acc[i][j][r], asv[j], ps);
          pd = fmaf(acc[i][j][r], adv[j], pd);
        }
        for (int off = 8; off; off >>= 1) {
          ps += __shfl_down(ps, off, 16);
          pd += __shfl_down(pd, off, 16);
        }
        if (ln == 0) {
          int rl = wr0 + i * 16 + quad * 4 + r;
          esp[rl * 2 + (wc0 >> 6)] = ps;
          edp[rl * 2 + (wc0 >> 6)] = pd;
        }
      }
    }
    __syncthreads();
    if (tid < 128) {
      int row = bm + tid;
      if (row < M) {
        int head = bn >> 7;
        es[(size_t)row * nh + head] = esp[tid * 2] + esp[tid * 2 + 1];
        ed[(size_t)row * nh + head] = edp[tid * 2] + edp[tid * 2 + 1];
      }
    }
  }
}

// ---------------- skinny MFMA GEMM, N=64, split-K, fp32 partials ----------------
__global__ __launch_bounds__(256) void gemm_mfma_n64(
    const unsigned short* __restrict__ A, int lda,
    const unsigned short* __restrict__ BT, int ldb,
    float* __restrict__ Cp, int M, int kchunk)
{
  const int LDT = 72;
  __shared__ unsigned short As[128 * 72];
  __shared__ unsigned short Bs[64 * 72];
  const int tid  = threadIdx.x;
  const int wave = tid >> 6;
  const int lane = tid & 63;
  const int ln   = lane & 15;
  const int quad = lane >> 4;
  const int ks   = blockIdx.x;
  const int bm   = blockIdx.y * 128;
  const int k_beg = ks * kchunk;
  const int k_end = k_beg + kchunk;
  const int arow = tid >> 1;
  const int akb  = (tid & 1) * 32;
  const int brow = tid >> 2;
  const int bkb  = (tid & 3) * 16;

  f32x4 acc[2][4];
  const f32x4 z4 = {0.f, 0.f, 0.f, 0.f};
#pragma unroll
  for (int i = 0; i < 2; ++i)
#pragma unroll
    for (int j = 0; j < 4; ++j) acc[i][j] = z4;

  for (int k0 = k_beg; k0 < k_end; k0 += 64) {
    const unsigned short* ap = A + (size_t)(bm + arow) * lda + k0 + akb;
#pragma unroll
    for (int q = 0; q < 4; ++q)
      *(bf16x8*)(&As[arow * LDT + akb + q * 8]) = *(const bf16x8*)(ap + q * 8);
    const unsigned short* bp = BT + (size_t)brow * ldb + k0 + bkb;
#pragma unroll
    for (int q = 0; q < 2; ++q)
      *(bf16x8*)(&Bs[brow * LDT + bkb + q * 8]) = *(const bf16x8*)(bp + q * 8);
    __syncthreads();
#pragma unroll
    for (int kk = 0; kk < 2; ++kk) {
      bf16x8 af[2], bfv[4];
#pragma unroll
      for (int i = 0; i < 2; ++i)
        af[i] = *(const bf16x8*)(&As[(wave * 32 + i * 16 + ln) * LDT + kk * 32 + quad * 8]);
#pragma unroll
      for (int j = 0; j < 4; ++j)
        bfv[j] = *(const bf16x8*)(&Bs[(j * 16 + ln) * LDT + kk * 32 + quad * 8]);
#pragma unroll
      for (int i = 0; i < 2; ++i)
#pragma unroll
        for (int j = 0; j < 4; ++j)
          acc[i][j] = __builtin_amdgcn_mfma_f32_16x16x32_bf16(af[i], bfv[j], acc[i][j], 0, 0, 0);
    }
    __syncthreads();
  }
#pragma unroll
  for (int i = 0; i < 2; ++i)
#pragma unroll
    for (int r = 0; r < 4; ++r) {
      int row = bm + wave * 32 + i * 16 + quad * 4 + r;
#pragma unroll
      for (int j = 0; j < 4; ++j)
        Cp[((size_t)ks * M + row) * 64 + j * 16 + ln] = acc[i][j][r];
    }
}

// ---------------- fp partial reduce + bias -> bf16 into z cols [512,576) ----------------
__global__ void fp_finish(const float* __restrict__ Cp, int ksplit, int M,
                          const float* __restrict__ bfp,
                          unsigned short* __restrict__ zb)
{
  const int g = blockIdx.x;
  const int j = threadIdx.x;
  float s = bfp[j];
  for (int ks = 0; ks < ksplit; ++ks) s += Cp[((size_t)ks * M + g) * 64 + j];
  zb[(size_t)g * 576 + 512 + j] = f2b_rne(s);
}

// ---------------- mlp partial reduce + bias + relu + fc2 dot -> out ----------------
__global__ void mlp_finish(const float* __restrict__ Cp, int ksplit, int M,
                           const float* __restrict__ bfc1,
                           const float* __restrict__ Wfc2, const float* __restrict__ bfc2,
                           float* __restrict__ out)
{
  const int g = blockIdx.x;
  const int j = threadIdx.x;
  float s = bfc1[j];
  for (int ks = 0; ks < ksplit; ++ks) s += Cp[((size_t)ks * M + g) * 64 + j];
  s = s > 0.f ? s : 0.f;
  float term = s * Wfc2[j];
  for (int off = 32; off; off >>= 1) term += __shfl_down(term, off, 64);
  if (j == 0) out[g] = term + bfc2[0];
}

// ---------------- CSR build ----------------
__global__ void count_deg(const int* __restrict__ ei, int E, int* __restrict__ deg)
{
  int e = blockIdx.x * 256 + threadIdx.x;
  if (e < E) atomicAdd(&deg[ei[E + e]], 1);
}

__global__ void fill_csr(const int* __restrict__ ei, int E, int* __restrict__ cursor,
                         const int* __restrict__ rowptr, int* __restrict__ csr_src)
{
  int e = blockIdx.x * 256 + threadIdx.x;
  if (e < E) {
    int d = ei[E + e];
    int pos = atomicAdd(&cursor[d], 1);
    csr_src[rowptr[d] + pos] = ei[e];
  }
}

__global__ void count_graph(const int* __restrict__ batch, int N, int* __restrict__ gcnt)
{
  int i = blockIdx.x * 256 + threadIdx.x;
  if (i < N) atomicAdd(&gcnt[batch[i]], 1);
}

// ---------------- 3-phase exclusive scan ----------------
__global__ void scan_p1(const int* __restrict__ vals, int n, int* __restrict__ bsum)
{
  __shared__ int red[256];
  int base = blockIdx.x * 1024;
  int t = threadIdx.x;
  int s = 0;
#pragma unroll
  for (int i = 0; i < 4; ++i) {
    int idx = base + i * 256 + t;
    if (idx < n) s += vals[idx];
  }
  red[t] = s;
  __syncthreads();
  for (int off = 128; off; off >>= 1) {
    if (t < off) red[t] += red[t + off];
    __syncthreads();
  }
  if (t == 0) bsum[blockIdx.x] = red[0];
}

__global__ void scan_p2(const int* __restrict__ bsum, int* __restrict__ bpre,
                        int nb, int* __restrict__ rowptr, int n)
{
  __shared__ int tmp[128];
  int t = threadIdx.x;
  int v = (t < nb) ? bsum[t] : 0;
  tmp[t] = v;
  __syncthreads();
  for (int off = 1; off < 128; off <<= 1) {
    int add = (t >= off) ? tmp[t - off] : 0;
    __syncthreads();
    tmp[t] += add;
    __syncthreads();
  }
  if (t < nb) bpre[t] = tmp[t] - v;
  if (t == 127) rowptr[n] = tmp[127];
}

__global__ void scan_p3(const int* __restrict__ vals, const int* __restrict__ bpre,
                        int n, int* __restrict__ rowptr)
{
  __shared__ int tmp[256];
  int t = threadIdx.x;
  int base = blockIdx.x * 1024 + t * 4;
  int v[4]; int s = 0;
#pragma unroll
  for (int i = 0; i < 4; ++i) {
    int idx = base + i;
    v[i] = (idx < n) ? vals[idx] : 0;
    s += v[i];
  }
  tmp[t] = s;
  __syncthreads();
  for (int off = 1; off < 256; off <<= 1) {
    int add = (t >= off) ? tmp[t - off] : 0;
    __syncthreads();
    tmp[t] += add;
    __syncthreads();
  }
  int run = bpre[blockIdx.x] + tmp[t] - s;
#pragma unroll
  for (int i = 0; i < 4; ++i) {
    int idx = base + i;
    if (idx < n) rowptr[idx] = run;
    run += v[i];
  }
}

// ---------------- normalized attention weights ----------------
__global__ void alpha_kernel(const float* __restrict__ es, const float* __restrict__ ed,
                             const int* __restrict__ rowptr, const int* __restrict__ csr_src,
                             float* __restrict__ w_csr, float* __restrict__ wself,
                             int N, int nh)
{
  int idx = blockIdx.x * 256 + threadIdx.x;
  if (idx >= N * nh) return;
  const int dst = idx / nh;
  const int h = idx - dst * nh;
  const float edh = ed[(size_t)dst * nh + h];
  const int beg = rowptr[dst], end = rowptr[dst + 1];
  float sum = 0.f;
  for (int e = beg; e < end; ++e) {
    int s = csr_src[e];
    float l = es[(size_t)s * nh + h] + edh;
    l = l >= 0.f ? l : NEG_SLOPE * l;
    float w = expf(l);
    w_csr[(size_t)e * nh + h] = w;
    sum += w;
  }
  float ls = es[(size_t)dst * nh + h] + edh;
  ls = ls >= 0.f ? ls : NEG_SLOPE * ls;
  float wsl = expf(ls);
  sum += wsl;
  const float inv = 1.0f / sum;
  for (int e = beg; e < end; ++e) w_csr[(size_t)e * nh + h] *= inv;
  wself[(size_t)dst * nh + h] = wsl * inv;
}

// ---------------- weighted gather aggregation + bias + ELU (bf16 out), x2 unroll ----------------
__global__ __launch_bounds__(256) void aggregate_b(
    const unsigned short* __restrict__ h,
    const float* __restrict__ w_csr, const float* __restrict__ wself,
    const int* __restrict__ rowptr, const int* __restrict__ csr_src,
    const float* __restrict__ bias, unsigned short* __restrict__ out,
    int N, int nh, int C)
{
  const int HC = nh * C;
  const int CH8 = HC >> 3;
  const int dpb = 256 / CH8;
  const int grp = threadIdx.x / CH8;
  const int lane = threadIdx.x - grp * CH8;
  const int dst = blockIdx.x * dpb + grp;
  if (dst >= N) return;
  const int ch = lane << 3;
  const int head = ch / C;
  const int beg = rowptr[dst], end = rowptr[dst + 1];
  float acc[8] = {0.f, 0.f, 0.f, 0.f, 0.f, 0.f, 0.f, 0.f};
  int e = beg;
  for (; e + 1 < end; e += 2) {
    int s0 = csr_src[e], s1 = csr_src[e + 1];
    float a0 = w_csr[(size_t)e * nh + head];
    float a1 = w_csr[(size_t)(e + 1) * nh + head];
    bf16x8 h0 = *(const bf16x8*)(h + (size_t)s0 * HC + ch);
    bf16x8 h1 = *(const bf16x8*)(h + (size_t)s1 * HC + ch);
#pragma unroll
    for (int r = 0; r < 8; ++r) acc[r] = fmaf(a0, b2f(h0[r]), acc[r]);
#pragma unroll
    for (int r = 0; r < 8; ++r) acc[r] = fmaf(a1, b2f(h1[r]), acc[r]);
  }
  if (e < end) {
    int s0 = csr_src[e];
    float a0 = w_csr[(size_t)e * nh + head];
    bf16x8 h0 = *(const bf16x8*)(h + (size_t)s0 * HC + ch);
#pragma unroll
    for (int r = 0; r < 8; ++r) acc[r] = fmaf(a0, b2f(h0[r]), acc[r]);
  }
  {
    float a = wself[(size_t)dst * nh + head];
    bf16x8 hv = *(const bf16x8*)(h + (size_t)dst * HC + ch);
#pragma unroll
    for (int r = 0; r < 8; ++r) acc[r] = fmaf(a, b2f(hv[r]), acc[r]);
  }
  bf16x8 o;
#pragma unroll
  for (int r = 0; r < 8; ++r) {
    float v = acc[r] + bias[ch + r];
    v = v > 0.f ? v : (expf(v) - 1.0f);
    o[r] = (short)f2b_rne(v);
  }
  *(bf16x8*)(out + (size_t)dst * HC + ch) = o;
}

// ---------------- per-graph mean pool (bf16 in) -> bf16 into z (stride 576) ----------------
__global__ void pool_mean_zb(const unsigned short* __restrict__ h, int in_stride,
                             const int* __restrict__ grp,
                             unsigned short* __restrict__ zb, int col_off)
{
  const int g = blockIdx.x;
  const int ch = threadIdx.x * 4;
  const int beg = grp[g], end = grp[g + 1];
  float4 acc = make_float4(0.f, 0.f, 0.f, 0.f);
  for (int i = beg; i < end; ++i) {
    bf16x4 v = *(const bf16x4*)(h + (size_t)i * in_stride + ch);
    acc.x += b2f(v[0]); acc.y += b2f(v[1]);
    acc.z += b2f(v[2]); acc.w += b2f(v[3]);
  }
  float inv = 1.0f / (float)max(end - beg, 1);
  bf16x4 o;
  o[0] = (short)f2b_rne(acc.x * inv);
  o[1] = (short)f2b_rne(acc.y * inv);
  o[2] = (short)f2b_rne(acc.z * inv);
  o[3] = (short)f2b_rne(acc.w * inv);
  *(bf16x4*)(zb + (size_t)g * 576 + col_off + ch) = o;
}

// ---------------- launcher ----------------
extern "C" void kernel_launch(void* const* d_in, const int* in_sizes, int n_in,
                              void* d_out, int out_size, void* d_ws, size_t ws_size,
                              hipStream_t stream)
{
  const float* x      = (const float*)d_in[0];
  const int*   ei     = (const int*)d_in[1];
  const int*   batch  = (const int*)d_in[2];
  const float* fp     = (const float*)d_in[3];
  const float* W1     = (const float*)d_in[4];
  const float* a_src1 = (const float*)d_in[5];
  const float* a_dst1 = (const float*)d_in[6];
  const float* b1     = (const float*)d_in[7];
  const float* W2     = (const float*)d_in[8];
  const float* a_src2 = (const float*)d_in[9];
  const float* a_dst2 = (const float*)d_in[10];
  const float* b2     = (const float*)d_in[11];
  const float* Wfp    = (const float*)d_in[12];
  const float* bfp    = (const float*)d_in[13];
  const float* Wfc1   = (const float*)d_in[14];
  const float* bfc1   = (const float*)d_in[15];
  const float* Wfc2   = (const float*)d_in[16];
  const float* bfc2   = (const float*)d_in[17];
  float* out = (float*)d_out;

  const int NN = in_sizes[0] / 128;
  const int E  = in_sizes[1] / 2;
  const int G  = in_sizes[3] / 2048;
  const int FIN = 128, H = 4, C1 = 64, C2 = 128;
  const int HC1 = H * C1;   // 256
  const int HC2 = H * C2;   // 512
  const int KFP = in_sizes[3] / G;   // 2048
  const int KZ  = HC2 + 64;          // 576
  const int KS_FP = 16;
  const int KS_Z  = 9;

  unsigned short *xb, *h1b, *h2b, *agg1b, *agg2b, *W1T, *W2T;
  unsigned short *fpb, *WfpT, *Wfc1T, *zb;
  float *es1, *ed1, *wself1, *w1, *es2, *ed2, *wself2, *w2, *Cp_fp, *Cp_z;
  int *deg, *cursor, *gcnt, *rowptr_n, *rowptr_g, *csr_src, *bsum, *bpre;

  auto build = [&](int npart) -> size_t {
    const int Cpart = HC2 / npart;
    char* base = (char*)d_ws;
    size_t off = 0;
    auto alloc = [&](size_t bytes) {
      char* p = base + off; off += (bytes + 15) & ~(size_t)15; return p;
    };
    size_t xb_sz  = ((size_t)NN * FIN * 2 + 15) & ~(size_t)15;
    size_t h1b_sz = ((size_t)NN * HC1 * 2 + 15) & ~(size_t)15;
    size_t h2b_sz = ((size_t)NN * Cpart * 2 + 15) & ~(size_t)15;
    size_t r0_sz  = xb_sz + h1b_sz; if (h2b_sz > r0_sz) r0_sz = h2b_sz;
    char* R0 = alloc(r0_sz);
    xb  = (unsigned short*)R0;
    h1b = (unsigned short*)(R0 + xb_sz);
    h2b = (unsigned short*)R0;
    agg1b  = (unsigned short*)alloc((size_t)NN * HC1 * 2);
    agg2b  = (unsigned short*)alloc((size_t)NN * Cpart * 2);
    es1    = (float*)alloc((size_t)NN * H * 4);
    ed1    = (float*)alloc((size_t)NN * H * 4);
    wself1 = (float*)alloc((size_t)NN * H * 4);
    w1     = (float*)alloc((size_t)E * H * 4);
    es2    = (float*)alloc((size_t)NN * H * 4);
    ed2    = (float*)alloc((size_t)NN * H * 4);
    wself2 = (float*)alloc((size_t)NN * H * 4);
    w2     = (float*)alloc((size_t)E * H * 4);
    zb     = (unsigned short*)alloc((size_t)G * KZ * 2);
    fpb    = (unsigned short*)alloc((size_t)G * KFP * 2);
    WfpT   = (unsigned short*)alloc((size_t)64 * KFP * 2);
    Wfc1T  = (unsigned short*)alloc((size_t)64 * KZ * 2);
    Cp_fp  = (float*)alloc((size_t)KS_FP * G * 64 * 4);
    Cp_z   = (float*)alloc((size_t)KS_Z * G * 64 * 4);
    W1T    = (unsigned short*)alloc((size_t)HC1 * FIN * 2);
    W2T    = (unsigned short*)alloc((size_t)HC2 * HC1 * 2);
    deg      = (int*)alloc((size_t)NN * 4);
    cursor   = (int*)alloc((size_t)NN * 4);
    gcnt     = (int*)alloc((size_t)G * 4);
    rowptr_n = (int*)alloc(((size_t)NN + 1) * 4);
    rowptr_g = (int*)alloc(((size_t)G + 1) * 4);
    csr_src  = (int*)alloc((size_t)E * 4);
    bsum     = (int*)alloc(128 * 4);
    bpre     = (int*)alloc(128 * 4);
    return off;
  };
  int npart = 1;
  if (build(1) > ws_size) { npart = 2; build(2); }
  const int HP = H / npart;
  const int Cpart = HP * C2;

  // ---- conversions ----
  {
    size_t nx = (size_t)NN * FIN;
    cvt_f2b<<<(int)((nx + 255) / 256), 256, 0, stream>>>(x, xb, nx);
    size_t nf = (size_t)G * KFP;
    cvt_f2b<<<2048, 256, 0, stream>>>(fp, fpb, nf);
    transpose_f2b<<<(FIN * HC1 + 255) / 256, 256, 0, stream>>>(W1, W1T, FIN, HC1);
    transpose_f2b<<<(HC1 * HC2 + 255) / 256, 256, 0, stream>>>(W2, W2T, HC1, HC2);
    transpose_f2b<<<(KFP * 64 + 255) / 256, 256, 0, stream>>>(Wfp, WfpT, KFP, 64);
    transpose_f2b<<<(KZ * 64 + 255) / 256, 256, 0, stream>>>(Wfc1, Wfc1T, KZ, 64);
  }

  // ---- fingerprint branch ----
  {
    dim3 gg(KS_FP, G / 128);
    gemm_mfma_n64<<<gg, 256, 0, stream>>>(fpb, KFP, WfpT, KFP, Cp_fp, G, KFP / KS_FP);
    fp_finish<<<G, 64, 0, stream>>>(Cp_fp, KS_FP, G, bfp, zb);
  }

  // ---- CSR by dst + graph segment ptrs ----
  hipMemsetAsync(deg, 0, sizeof(int) * (2 * (size_t)NN + G), stream);
  count_deg<<<(E + 255) / 256, 256, 0, stream>>>(ei, E, deg);
  {
    int nb = (NN + 1023) / 1024;
    scan_p1<<<nb, 256, 0, stream>>>(deg, NN, bsum);
    scan_p2<<<1, 128, 0, stream>>>(bsum, bpre, nb, rowptr_n, NN);
    scan_p3<<<nb, 256, 0, stream>>>(deg, bpre, NN, rowptr_n);
  }
  fill_csr<<<(E + 255) / 256, 256, 0, stream>>>(ei, E, cursor, rowptr_n, csr_src);
  count_graph<<<(NN + 255) / 256, 256, 0, stream>>>(batch, NN, gcnt);
  {
    int nb = (G + 1023) / 1024;
    scan_p1<<<nb, 256, 0, stream>>>(gcnt, G, bsum);
    scan_p2<<<1, 128, 0, stream>>>(bsum, bpre, nb, rowptr_g, G);
    scan_p3<<<nb, 256, 0, stream>>>(gcnt, bpre, G, rowptr_g);
  }

  // ---- conv1: GEMM (+fused e) -> alpha -> aggregate ----
  {
    dim3 gg(HC1 / 128, (NN + 127) / 128);
    gemm_mfma<64><<<gg, 256, 0, stream>>>(xb, W1T, h1b, NN, HC1, FIN,
                                          a_src1, a_dst1, es1, ed1, H);
  }
  alpha_kernel<<<(NN * H + 255) / 256, 256, 0, stream>>>(es1, ed1, rowptr_n, csr_src,
                                                         w1, wself1, NN, H);
  aggregate_b<<<(NN + 7) / 8, 256, 0, stream>>>(h1b, w1, wself1, rowptr_n, csr_src,
                                                b1, agg1b, NN, H, C1);

  // ---- conv2, by partition: GEMM (+fused e) -> alpha -> aggregate -> pool ----
  for (int p = 0; p < npart; ++p) {
    dim3 gg(Cpart / 128, (NN + 127) / 128);
    gemm_mfma<128><<<gg, 256, 0, stream>>>(agg1b, W2T + (size_t)p * Cpart * HC1, h2b,
                                           NN, Cpart, HC1,
                                           a_src2 + (size_t)p * Cpart,
                                           a_dst2 + (size_t)p * Cpart,
                                           es2, ed2, HP);
    alpha_kernel<<<(NN * HP + 255) / 256, 256, 0, stream>>>(es2, ed2, rowptr_n, csr_src,
                                                            w2, wself2, NN, HP);
    {
      int CH8 = Cpart >> 3;
      int dpb = 256 / CH8;
      aggregate_b<<<(NN + dpb - 1) / dpb, 256, 0, stream>>>(
          h2b, w2, wself2, rowptr_n, csr_src, b2 + (size_t)p * Cpart, agg2b, NN, HP, C2);
    }
    pool_mean_zb<<<G, Cpart / 4, 0, stream>>>(agg2b, Cpart, rowptr_g, zb, p * Cpart);
  }

  // ---- head ----
  {
    dim3 gg(KS_Z, G / 128);
    gemm_mfma_n64<<<gg, 256, 0, stream>>>(zb, KZ, Wfc1T, KZ, Cp_z, G, KZ / KS_Z);
    mlp_finish<<<G, 64, 0, stream>>>(Cp_z, KS_Z, G, bfc1, Wfc2, bfc2, out);
  }
}

// Round 9
// 520.908 us; speedup vs baseline: 3.5312x; 1.1683x over previous
//
#include <hip/hip_runtime.h>
#include <math.h>

#define NEG_SLOPE 0.2f

typedef __attribute__((ext_vector_type(8))) short bf16x8;   // 8 bf16 (4 VGPRs)
typedef __attribute__((ext_vector_type(4))) float f32x4;    // MFMA acc

__device__ __forceinline__ float b2f(short s) {
  return __uint_as_float(((unsigned int)(unsigned short)s) << 16);
}
__device__ __forceinline__ unsigned short f2b_rne(float f) {
  unsigned int u = __float_as_uint(f);
  u = (u + 0x7FFF + ((u >> 16) & 1)) >> 16;
  return (unsigned short)u;
}

// ---------------- fp32 -> bf16 elementwise ----------------
__global__ void cvt_f2b(const float* __restrict__ in, unsigned short* __restrict__ out, size_t n)
{
  size_t i = (size_t)blockIdx.x * 256 + threadIdx.x;
  size_t stride = (size_t)gridDim.x * 256;
  for (; i < n; i += stride) out[i] = f2b_rne(in[i]);
}

// ---------------- W [K,N] f32 -> WT [N,K] bf16 ----------------
__global__ void transpose_f2b(const float* __restrict__ W, unsigned short* __restrict__ WT,
                              int K, int N)
{
  int idx = blockIdx.x * 256 + threadIdx.x;
  if (idx < K * N) {
    int k = idx / N, n = idx - k * N;
    WT[(size_t)n * K + k] = f2b_rne(W[idx]);
  }
}

// ---------------- MFMA GEMM + fused e epilogue, register-prefetch dbuf ----------------
// A bf16 [M,K] row-major, BT bf16 [N,K] row-major. BM=BN=128, BK=32, 4 waves.
// EMODE = channels-per-head (64 or 128).
template<int EMODE>
__global__ __launch_bounds__(256) void gemm_mfma(
    const unsigned short* __restrict__ A, const unsigned short* __restrict__ BT,
    unsigned short* __restrict__ Cout, int M, int N, int K,
    const float* __restrict__ a_src, const float* __restrict__ a_dst,
    float* __restrict__ es, float* __restrict__ ed, int nh)
{
  const int LDT = 40;
  __shared__ unsigned short As[128 * 40];
  __shared__ unsigned short Bs[128 * 40];
  const int tid  = threadIdx.x;
  const int wave = tid >> 6;
  const int lane = tid & 63;
  const int ln   = lane & 15;
  const int quad = lane >> 4;
  const int wr0  = (wave >> 1) * 64;
  const int wc0  = (wave & 1) * 64;
  const int bm   = blockIdx.y * 128;
  const int bn   = blockIdx.x * 128;
  const int srow  = tid >> 2;
  const int skoff = (tid & 3) * 8;

  f32x4 acc[4][4];
  const f32x4 z4 = {0.f, 0.f, 0.f, 0.f};
#pragma unroll
  for (int i = 0; i < 4; ++i)
#pragma unroll
    for (int j = 0; j < 4; ++j) acc[i][j] = z4;

  const bf16x8 zb8 = {0, 0, 0, 0, 0, 0, 0, 0};
  bf16x8 pa[2] = {zb8, zb8}, pb[2] = {zb8, zb8};
  bf16x8 na[2] = {zb8, zb8}, nb[2] = {zb8, zb8};
  // prefetch tile 0
#pragma unroll
  for (int p = 0; p < 2; ++p) {
    int r = srow + p * 64;
    pa[p] = (bm + r < M) ? *(const bf16x8*)(A + (size_t)(bm + r) * K + skoff) : zb8;
    pb[p] = *(const bf16x8*)(BT + (size_t)(bn + r) * K + skoff);
  }

  for (int k0 = 0; k0 < K; k0 += 32) {
#pragma unroll
    for (int p = 0; p < 2; ++p) {
      int r = srow + p * 64;
      *(bf16x8*)(&As[r * LDT + skoff]) = pa[p];
      *(bf16x8*)(&Bs[r * LDT + skoff]) = pb[p];
    }
    __syncthreads();
    if (k0 + 32 < K) {
      int kn = k0 + 32;
#pragma unroll
      for (int p = 0; p < 2; ++p) {
        int r = srow + p * 64;
        na[p] = (bm + r < M) ? *(const bf16x8*)(A + (size_t)(bm + r) * K + kn + skoff) : zb8;
        nb[p] = *(const bf16x8*)(BT + (size_t)(bn + r) * K + kn + skoff);
      }
    }
    bf16x8 af[4], bfv[4];
#pragma unroll
    for (int i = 0; i < 4; ++i)
      af[i] = *(const bf16x8*)(&As[(wr0 + i * 16 + ln) * LDT + quad * 8]);
#pragma unroll
    for (int j = 0; j < 4; ++j)
      bfv[j] = *(const bf16x8*)(&Bs[(wc0 + j * 16 + ln) * LDT + quad * 8]);
#pragma unroll
    for (int i = 0; i < 4; ++i)
#pragma unroll
      for (int j = 0; j < 4; ++j)
        acc[i][j] = __builtin_amdgcn_mfma_f32_16x16x32_bf16(af[i], bfv[j], acc[i][j], 0, 0, 0);
    __syncthreads();
#pragma unroll
    for (int p = 0; p < 2; ++p) { pa[p] = na[p]; pb[p] = nb[p]; }
  }

  // ---- C store (bf16) ----
#pragma unroll
  for (int i = 0; i < 4; ++i) {
#pragma unroll
    for (int r = 0; r < 4; ++r) {
      int row = bm + wr0 + i * 16 + quad * 4 + r;
      if (row >= M) continue;
#pragma unroll
      for (int j = 0; j < 4; ++j) {
        int col = bn + wc0 + j * 16 + ln;
        Cout[(size_t)row * N + col] = f2b_rne(acc[i][j][r]);
      }
    }
  }

  // ---- fused e_src/e_dst ----
  float asv[4], adv[4];
#pragma unroll
  for (int j = 0; j < 4; ++j) {
    int col = bn + wc0 + j * 16 + ln;
    asv[j] = a_src[col];
    adv[j] = a_dst[col];
  }
  if (EMODE == 64) {
    const int head = (bn + wc0) >> 6;
#pragma unroll
    for (int i = 0; i < 4; ++i) {
#pragma unroll
      for (int r = 0; r < 4; ++r) {
        float ps = 0.f, pd = 0.f;
#pragma unroll
        for (int j = 0; j < 4; ++j) {
          ps = fmaf(acc[i][j][r], asv[j], ps);
          pd = fmaf(acc[i][j][r], adv[j], pd);
        }
        for (int off = 8; off; off >>= 1) {
          ps += __shfl_down(ps, off, 16);
          pd += __shfl_down(pd, off, 16);
        }
        if (ln == 0) {
          int row = bm + wr0 + i * 16 + quad * 4 + r;
          if (row < M) {
            es[(size_t)row * nh + head] = ps;
            ed[(size_t)row * nh + head] = pd;
          }
        }
      }
    }
  } else {  // EMODE == 128: block = one head; combine col-halves via LDS
    float* esp = (float*)As;          // [128][2]
    float* edp = esp + 256;
#pragma unroll
    for (int i = 0; i < 4; ++i) {
#pragma unroll
      for (int r = 0; r < 4; ++r) {
        float ps = 0.f, pd = 0.f;
#pragma unroll
        for (int j = 0; j < 4; ++j) {
          ps = fmaf(acc[i][j][r], asv[j], ps);
          pd = fmaf(acc[i][j][r], adv[j], pd);
        }
        for (int off = 8; off; off >>= 1) {
          ps += __shfl_down(ps, off, 16);
          pd += __shfl_down(pd, off, 16);
        }
        if (ln == 0) {
          int rl = wr0 + i * 16 + quad * 4 + r;
          esp[rl * 2 + (wc0 >> 6)] = ps;
          edp[rl * 2 + (wc0 >> 6)] = pd;
        }
      }
    }
    __syncthreads();
    if (tid < 128) {
      int row = bm + tid;
      if (row < M) {
        int head = bn >> 7;
        es[(size_t)row * nh + head] = esp[tid * 2] + esp[tid * 2 + 1];
        ed[(size_t)row * nh + head] = edp[tid * 2] + edp[tid * 2 + 1];
      }
    }
  }
}

// ---------------- skinny MFMA GEMM, N=64, split-K, fp32 partials ----------------
__global__ __launch_bounds__(256) void gemm_mfma_n64(
    const unsigned short* __restrict__ A, int lda,
    const unsigned short* __restrict__ BT, int ldb,
    float* __restrict__ Cp, int M, int kchunk)
{
  const int LDT = 72;
  __shared__ unsigned short As[128 * 72];
  __shared__ unsigned short Bs[64 * 72];
  const int tid  = threadIdx.x;
  const int wave = tid >> 6;
  const int lane = tid & 63;
  const int ln   = lane & 15;
  const int quad = lane >> 4;
  const int ks   = blockIdx.x;
  const int bm   = blockIdx.y * 128;
  const int k_beg = ks * kchunk;
  const int k_end = k_beg + kchunk;
  const int arow = tid >> 1;
  const int akb  = (tid & 1) * 32;
  const int brow = tid >> 2;
  const int bkb  = (tid & 3) * 16;

  f32x4 acc[2][4];
  const f32x4 z4 = {0.f, 0.f, 0.f, 0.f};
#pragma unroll
  for (int i = 0; i < 2; ++i)
#pragma unroll
    for (int j = 0; j < 4; ++j) acc[i][j] = z4;

  for (int k0 = k_beg; k0 < k_end; k0 += 64) {
    const unsigned short* ap = A + (size_t)(bm + arow) * lda + k0 + akb;
#pragma unroll
    for (int q = 0; q < 4; ++q)
      *(bf16x8*)(&As[arow * LDT + akb + q * 8]) = *(const bf16x8*)(ap + q * 8);
    const unsigned short* bp = BT + (size_t)brow * ldb + k0 + bkb;
#pragma unroll
    for (int q = 0; q < 2; ++q)
      *(bf16x8*)(&Bs[brow * LDT + bkb + q * 8]) = *(const bf16x8*)(bp + q * 8);
    __syncthreads();
#pragma unroll
    for (int kk = 0; kk < 2; ++kk) {
      bf16x8 af[2], bfv[4];
#pragma unroll
      for (int i = 0; i < 2; ++i)
        af[i] = *(const bf16x8*)(&As[(wave * 32 + i * 16 + ln) * LDT + kk * 32 + quad * 8]);
#pragma unroll
      for (int j = 0; j < 4; ++j)
        bfv[j] = *(const bf16x8*)(&Bs[(j * 16 + ln) * LDT + kk * 32 + quad * 8]);
#pragma unroll
      for (int i = 0; i < 2; ++i)
#pragma unroll
        for (int j = 0; j < 4; ++j)
          acc[i][j] = __builtin_amdgcn_mfma_f32_16x16x32_bf16(af[i], bfv[j], acc[i][j], 0, 0, 0);
    }
    __syncthreads();
  }
#pragma unroll
  for (int i = 0; i < 2; ++i)
#pragma unroll
    for (int r = 0; r < 4; ++r) {
      int row = bm + wave * 32 + i * 16 + quad * 4 + r;
#pragma unroll
      for (int j = 0; j < 4; ++j)
        Cp[((size_t)ks * M + row) * 64 + j * 16 + ln] = acc[i][j][r];
    }
}

// ---------------- fp partial reduce + bias -> bf16 into z cols [512,576) ----------------
__global__ void fp_finish(const float* __restrict__ Cp, int ksplit, int M,
                          const float* __restrict__ bfp,
                          unsigned short* __restrict__ zb)
{
  const int g = blockIdx.x;
  const int j = threadIdx.x;
  float s = bfp[j];
  for (int ks = 0; ks < ksplit; ++ks) s += Cp[((size_t)ks * M + g) * 64 + j];
  zb[(size_t)g * 576 + 512 + j] = f2b_rne(s);
}

// ---------------- mlp partial reduce + bias + relu + fc2 dot -> out ----------------
__global__ void mlp_finish(const float* __restrict__ Cp, int ksplit, int M,
                           const float* __restrict__ bfc1,
                           const float* __restrict__ Wfc2, const float* __restrict__ bfc2,
                           float* __restrict__ out)
{
  const int g = blockIdx.x;
  const int j = threadIdx.x;
  float s = bfc1[j];
  for (int ks = 0; ks < ksplit; ++ks) s += Cp[((size_t)ks * M + g) * 64 + j];
  s = s > 0.f ? s : 0.f;
  float term = s * Wfc2[j];
  for (int off = 32; off; off >>= 1) term += __shfl_down(term, off, 64);
  if (j == 0) out[g] = term + bfc2[0];
}

// ---------------- CSR build ----------------
__global__ void count_deg(const int* __restrict__ ei, int E, int* __restrict__ deg)
{
  int e = blockIdx.x * 256 + threadIdx.x;
  if (e < E) atomicAdd(&deg[ei[E + e]], 1);
}

__global__ void fill_csr(const int* __restrict__ ei, int E, int* __restrict__ cursor,
                         const int* __restrict__ rowptr, int* __restrict__ csr_src)
{
  int e = blockIdx.x * 256 + threadIdx.x;
  if (e < E) {
    int d = ei[E + e];
    int pos = atomicAdd(&cursor[d], 1);
    csr_src[rowptr[d] + pos] = ei[e];
  }
}

__global__ void count_graph(const int* __restrict__ batch, int N, int* __restrict__ gcnt)
{
  int i = blockIdx.x * 256 + threadIdx.x;
  if (i < N) atomicAdd(&gcnt[batch[i]], 1);
}

// ---------------- 3-phase exclusive scan ----------------
__global__ void scan_p1(const int* __restrict__ vals, int n, int* __restrict__ bsum)
{
  __shared__ int red[256];
  int base = blockIdx.x * 1024;
  int t = threadIdx.x;
  int s = 0;
#pragma unroll
  for (int i = 0; i < 4; ++i) {
    int idx = base + i * 256 + t;
    if (idx < n) s += vals[idx];
  }
  red[t] = s;
  __syncthreads();
  for (int off = 128; off; off >>= 1) {
    if (t < off) red[t] += red[t + off];
    __syncthreads();
  }
  if (t == 0) bsum[blockIdx.x] = red[0];
}

__global__ void scan_p2(const int* __restrict__ bsum, int* __restrict__ bpre,
                        int nb, int* __restrict__ rowptr, int n)
{
  __shared__ int tmp[128];
  int t = threadIdx.x;
  int v = (t < nb) ? bsum[t] : 0;
  tmp[t] = v;
  __syncthreads();
  for (int off = 1; off < 128; off <<= 1) {
    int add = (t >= off) ? tmp[t - off] : 0;
    __syncthreads();
    tmp[t] += add;
    __syncthreads();
  }
  if (t < nb) bpre[t] = tmp[t] - v;
  if (t == 127) rowptr[n] = tmp[127];
}

__global__ void scan_p3(const int* __restrict__ vals, const int* __restrict__ bpre,
                        int n, int* __restrict__ rowptr)
{
  __shared__ int tmp[256];
  int t = threadIdx.x;
  int base = blockIdx.x * 1024 + t * 4;
  int v[4]; int s = 0;
#pragma unroll
  for (int i = 0; i < 4; ++i) {
    int idx = base + i;
    v[i] = (idx < n) ? vals[idx] : 0;
    s += v[i];
  }
  tmp[t] = s;
  __syncthreads();
  for (int off = 1; off < 256; off <<= 1) {
    int add = (t >= off) ? tmp[t - off] : 0;
    __syncthreads();
    tmp[t] += add;
    __syncthreads();
  }
  int run = bpre[blockIdx.x] + tmp[t] - s;
#pragma unroll
  for (int i = 0; i < 4; ++i) {
    int idx = base + i;
    if (idx < n) rowptr[idx] = run;
    run += v[i];
  }
}

// ---------------- normalized attention weights ----------------
__global__ void alpha_kernel(const float* __restrict__ es, const float* __restrict__ ed,
                             const int* __restrict__ rowptr, const int* __restrict__ csr_src,
                             float* __restrict__ w_csr, float* __restrict__ wself,
                             int N, int nh)
{
  int idx = blockIdx.x * 256 + threadIdx.x;
  if (idx >= N * nh) return;
  const int dst = idx / nh;
  const int h = idx - dst * nh;
  const float edh = ed[(size_t)dst * nh + h];
  const int beg = rowptr[dst], end = rowptr[dst + 1];
  float sum = 0.f;
  for (int e = beg; e < end; ++e) {
    int s = csr_src[e];
    float l = es[(size_t)s * nh + h] + edh;
    l = l >= 0.f ? l : NEG_SLOPE * l;
    float w = expf(l);
    w_csr[(size_t)e * nh + h] = w;
    sum += w;
  }
  float ls = es[(size_t)dst * nh + h] + edh;
  ls = ls >= 0.f ? ls : NEG_SLOPE * ls;
  float wsl = expf(ls);
  sum += wsl;
  const float inv = 1.0f / sum;
  for (int e = beg; e < end; ++e) w_csr[(size_t)e * nh + h] *= inv;
  wself[(size_t)dst * nh + h] = wsl * inv;
}

// ---------------- conv1 aggregate: gather + bias + ELU -> bf16 out ----------------
__global__ __launch_bounds__(256) void aggregate_b(
    const unsigned short* __restrict__ h,
    const float* __restrict__ w_csr, const float* __restrict__ wself,
    const int* __restrict__ rowptr, const int* __restrict__ csr_src,
    const float* __restrict__ bias, unsigned short* __restrict__ out,
    int N, int nh, int C)
{
  const int HC = nh * C;
  const int CH8 = HC >> 3;
  const int dpb = 256 / CH8;
  const int grp = threadIdx.x / CH8;
  const int lane = threadIdx.x - grp * CH8;
  const int dst = blockIdx.x * dpb + grp;
  if (dst >= N) return;
  const int ch = lane << 3;
  const int head = ch / C;
  const int beg = rowptr[dst], end = rowptr[dst + 1];
  float acc[8] = {0.f, 0.f, 0.f, 0.f, 0.f, 0.f, 0.f, 0.f};
  int e = beg;
  for (; e + 1 < end; e += 2) {
    int s0 = csr_src[e], s1 = csr_src[e + 1];
    float a0 = w_csr[(size_t)e * nh + head];
    float a1 = w_csr[(size_t)(e + 1) * nh + head];
    bf16x8 h0 = *(const bf16x8*)(h + (size_t)s0 * HC + ch);
    bf16x8 h1 = *(const bf16x8*)(h + (size_t)s1 * HC + ch);
#pragma unroll
    for (int r = 0; r < 8; ++r) acc[r] = fmaf(a0, b2f(h0[r]), acc[r]);
#pragma unroll
    for (int r = 0; r < 8; ++r) acc[r] = fmaf(a1, b2f(h1[r]), acc[r]);
  }
  if (e < end) {
    int s0 = csr_src[e];
    float a0 = w_csr[(size_t)e * nh + head];
    bf16x8 h0 = *(const bf16x8*)(h + (size_t)s0 * HC + ch);
#pragma unroll
    for (int r = 0; r < 8; ++r) acc[r] = fmaf(a0, b2f(h0[r]), acc[r]);
  }
  {
    float a = wself[(size_t)dst * nh + head];
    bf16x8 hv = *(const bf16x8*)(h + (size_t)dst * HC + ch);
#pragma unroll
    for (int r = 0; r < 8; ++r) acc[r] = fmaf(a, b2f(hv[r]), acc[r]);
  }
  bf16x8 o;
#pragma unroll
  for (int r = 0; r < 8; ++r) {
    float v = acc[r] + bias[ch + r];
    v = v > 0.f ? v : (expf(v) - 1.0f);
    o[r] = (short)f2b_rne(v);
  }
  *(bf16x8*)(out + (size_t)dst * HC + ch) = o;
}

// ---------------- conv2 aggregate + ELU + mean-pool fused, one block per graph ----------------
// h [N,512] bf16, nh=4, C=128. 4 waves; wave w handles nodes gbeg+w, step 4;
// 64 lanes x 8ch = 512 ch. Register pool partials, LDS cross-wave reduce.
// Deterministic (no atomics).
__global__ __launch_bounds__(256) void agg_pool(
    const unsigned short* __restrict__ h,
    const float* __restrict__ w_csr, const float* __restrict__ wself,
    const int* __restrict__ rowptr, const int* __restrict__ csr_src,
    const float* __restrict__ bias, const int* __restrict__ grp,
    unsigned short* __restrict__ zb)
{
  const int g = blockIdx.x;
  const int wave = threadIdx.x >> 6;
  const int lane = threadIdx.x & 63;
  const int ch = lane << 3;
  const int head = lane >> 4;          // ch/128
  const int gbeg = grp[g], gend = grp[g + 1];
  float bch[8];
#pragma unroll
  for (int r = 0; r < 8; ++r) bch[r] = bias[ch + r];
  float pool[8] = {0.f, 0.f, 0.f, 0.f, 0.f, 0.f, 0.f, 0.f};

  for (int node = gbeg + wave; node < gend; node += 4) {
    const int beg = rowptr[node], end = rowptr[node + 1];
    float acc[8] = {0.f, 0.f, 0.f, 0.f, 0.f, 0.f, 0.f, 0.f};
    int e = beg;
    for (; e + 1 < end; e += 2) {
      int s0 = csr_src[e], s1 = csr_src[e + 1];
      float a0 = w_csr[(size_t)e * 4 + head];
      float a1 = w_csr[(size_t)(e + 1) * 4 + head];
      bf16x8 h0 = *(const bf16x8*)(h + (size_t)s0 * 512 + ch);
      bf16x8 h1 = *(const bf16x8*)(h + (size_t)s1 * 512 + ch);
#pragma unroll
      for (int r = 0; r < 8; ++r) acc[r] = fmaf(a0, b2f(h0[r]), acc[r]);
#pragma unroll
      for (int r = 0; r < 8; ++r) acc[r] = fmaf(a1, b2f(h1[r]), acc[r]);
    }
    if (e < end) {
      int s0 = csr_src[e];
      float a0 = w_csr[(size_t)e * 4 + head];
      bf16x8 h0 = *(const bf16x8*)(h + (size_t)s0 * 512 + ch);
#pragma unroll
      for (int r = 0; r < 8; ++r) acc[r] = fmaf(a0, b2f(h0[r]), acc[r]);
    }
    {
      float a = wself[(size_t)node * 4 + head];
      bf16x8 hv = *(const bf16x8*)(h + (size_t)node * 512 + ch);
#pragma unroll
      for (int r = 0; r < 8; ++r) acc[r] = fmaf(a, b2f(hv[r]), acc[r]);
    }
#pragma unroll
    for (int r = 0; r < 8; ++r) {
      float v = acc[r] + bch[r];
      v = v > 0.f ? v : (expf(v) - 1.0f);   // ELU
      pool[r] += v;
    }
  }

  __shared__ float red[4][512];
#pragma unroll
  for (int r = 0; r < 8; ++r) red[wave][ch + r] = pool[r];
  __syncthreads();
  const float inv = 1.0f / (float)max(gend - gbeg, 1);
  // 256 threads x 2 channels
#pragma unroll
  for (int k = 0; k < 2; ++k) {
    int c = threadIdx.x + k * 256;
    float s = (red[0][c] + red[1][c]) + (red[2][c] + red[3][c]);
    zb[(size_t)g * 576 + c] = f2b_rne(s * inv);
  }
}

// ---------------- launcher ----------------
extern "C" void kernel_launch(void* const* d_in, const int* in_sizes, int n_in,
                              void* d_out, int out_size, void* d_ws, size_t ws_size,
                              hipStream_t stream)
{
  const float* x      = (const float*)d_in[0];
  const int*   ei     = (const int*)d_in[1];
  const int*   batch  = (const int*)d_in[2];
  const float* fp     = (const float*)d_in[3];
  const float* W1     = (const float*)d_in[4];
  const float* a_src1 = (const float*)d_in[5];
  const float* a_dst1 = (const float*)d_in[6];
  const float* b1     = (const float*)d_in[7];
  const float* W2     = (const float*)d_in[8];
  const float* a_src2 = (const float*)d_in[9];
  const float* a_dst2 = (const float*)d_in[10];
  const float* b2     = (const float*)d_in[11];
  const float* Wfp    = (const float*)d_in[12];
  const float* bfp    = (const float*)d_in[13];
  const float* Wfc1   = (const float*)d_in[14];
  const float* bfc1   = (const float*)d_in[15];
  const float* Wfc2   = (const float*)d_in[16];
  const float* bfc2   = (const float*)d_in[17];
  float* out = (float*)d_out;

  const int NN = in_sizes[0] / 128;
  const int E  = in_sizes[1] / 2;
  const int G  = in_sizes[3] / 2048;
  const int FIN = 128, H = 4, C1 = 64, C2 = 128;
  const int HC1 = H * C1;   // 256
  const int HC2 = H * C2;   // 512
  const int KFP = in_sizes[3] / G;   // 2048
  const int KZ  = HC2 + 64;          // 576
  const int KS_FP = 16;
  const int KS_Z  = 9;

  // ---- workspace: liverange-overlaid regions (~176 MB total) ----
  char* base = (char*)d_ws;
  size_t off = 0;
  auto alloc = [&](size_t bytes) {
    char* p = base + off; off += (bytes + 255) & ~(size_t)255; return p;
  };
  // Region A: early xb+h1b; late h2b
  size_t xb_sz  = ((size_t)NN * FIN * 2 + 255) & ~(size_t)255;
  size_t h1b_sz = (size_t)NN * HC1 * 2;
  size_t h2b_sz = (size_t)NN * HC2 * 2;
  size_t rA = xb_sz + h1b_sz; if (h2b_sz > rA) rA = h2b_sz;
  char* RA = alloc(rA);
  unsigned short* xb  = (unsigned short*)RA;
  unsigned short* h1b = (unsigned short*)(RA + xb_sz);
  unsigned short* h2b = (unsigned short*)RA;
  // Region B: early fpb+Cp_fp (fp branch); late agg1b
  size_t fpb_sz  = ((size_t)G * KFP * 2 + 255) & ~(size_t)255;
  size_t cpfp_sz = (size_t)KS_FP * G * 64 * 4;
  size_t agg1_sz = (size_t)NN * HC1 * 2;
  size_t rB = fpb_sz + cpfp_sz; if (agg1_sz > rB) rB = agg1_sz;
  char* RB = alloc(rB);
  unsigned short* fpb   = (unsigned short*)RB;
  float*          Cp_fp = (float*)(RB + fpb_sz);
  unsigned short* agg1b = (unsigned short*)RB;
  // Region C: conv1 attn buffers; reused by conv2
  float* w1     = (float*)alloc((size_t)E * H * 4);
  float* wself1 = (float*)alloc((size_t)NN * H * 4);
  float* es1    = (float*)alloc((size_t)NN * H * 4);
  float* ed1    = (float*)alloc((size_t)NN * H * 4);
  float* w2 = w1, *wself2 = wself1, *es2 = es1, *ed2 = ed1;
  // Persistent small buffers
  unsigned short* zb    = (unsigned short*)alloc((size_t)G * KZ * 2);
  float*          Cp_z  = (float*)alloc((size_t)KS_Z * G * 64 * 4);
  unsigned short* W1T   = (unsigned short*)alloc((size_t)HC1 * FIN * 2);
  unsigned short* W2T   = (unsigned short*)alloc((size_t)HC2 * HC1 * 2);
  unsigned short* WfpT  = (unsigned short*)alloc((size_t)64 * KFP * 2);
  unsigned short* Wfc1T = (unsigned short*)alloc((size_t)64 * KZ * 2);
  // int arena: deg/cursor/gcnt MUST be contiguous (single memset covers them)
  int* iarena   = (int*)alloc(((size_t)2 * NN + G) * 4);
  int* deg      = iarena;
  int* cursor   = iarena + NN;
  int* gcnt     = iarena + 2 * NN;
  int* rowptr_n = (int*)alloc(((size_t)NN + 1) * 4);
  int* rowptr_g = (int*)alloc(((size_t)G + 1) * 4);
  int* csr_src  = (int*)alloc((size_t)E * 4);
  int* bsum     = (int*)alloc(128 * 4);
  int* bpre     = (int*)alloc(128 * 4);

  // ---- conversions ----
  {
    size_t nx = (size_t)NN * FIN;
    cvt_f2b<<<(int)((nx + 255) / 256), 256, 0, stream>>>(x, xb, nx);
    size_t nf = (size_t)G * KFP;
    cvt_f2b<<<2048, 256, 0, stream>>>(fp, fpb, nf);
    transpose_f2b<<<(FIN * HC1 + 255) / 256, 256, 0, stream>>>(W1, W1T, FIN, HC1);
    transpose_f2b<<<(HC1 * HC2 + 255) / 256, 256, 0, stream>>>(W2, W2T, HC1, HC2);
    transpose_f2b<<<(KFP * 64 + 255) / 256, 256, 0, stream>>>(Wfp, WfpT, KFP, 64);
    transpose_f2b<<<(KZ * 64 + 255) / 256, 256, 0, stream>>>(Wfc1, Wfc1T, KZ, 64);
  }

  // ---- fingerprint branch (finishes before agg1b is written — same stream) ----
  {
    dim3 gg(KS_FP, G / 128);
    gemm_mfma_n64<<<gg, 256, 0, stream>>>(fpb, KFP, WfpT, KFP, Cp_fp, G, KFP / KS_FP);
    fp_finish<<<G, 64, 0, stream>>>(Cp_fp, KS_FP, G, bfp, zb);
  }

  // ---- CSR by dst + graph segment ptrs ----
  hipMemsetAsync(iarena, 0, sizeof(int) * ((size_t)2 * NN + G), stream);
  count_deg<<<(E + 255) / 256, 256, 0, stream>>>(ei, E, deg);
  {
    int nb = (NN + 1023) / 1024;
    scan_p1<<<nb, 256, 0, stream>>>(deg, NN, bsum);
    scan_p2<<<1, 128, 0, stream>>>(bsum, bpre, nb, rowptr_n, NN);
    scan_p3<<<nb, 256, 0, stream>>>(deg, bpre, NN, rowptr_n);
  }
  fill_csr<<<(E + 255) / 256, 256, 0, stream>>>(ei, E, cursor, rowptr_n, csr_src);
  count_graph<<<(NN + 255) / 256, 256, 0, stream>>>(batch, NN, gcnt);
  {
    int nb = (G + 1023) / 1024;
    scan_p1<<<nb, 256, 0, stream>>>(gcnt, G, bsum);
    scan_p2<<<1, 128, 0, stream>>>(bsum, bpre, nb, rowptr_g, G);
    scan_p3<<<nb, 256, 0, stream>>>(gcnt, bpre, G, rowptr_g);
  }

  // ---- conv1: GEMM (+fused e) -> alpha -> aggregate ----
  {
    dim3 gg(HC1 / 128, (NN + 127) / 128);
    gemm_mfma<64><<<gg, 256, 0, stream>>>(xb, W1T, h1b, NN, HC1, FIN,
                                          a_src1, a_dst1, es1, ed1, H);
  }
  alpha_kernel<<<(NN * H + 255) / 256, 256, 0, stream>>>(es1, ed1, rowptr_n, csr_src,
                                                         w1, wself1, NN, H);
  aggregate_b<<<(NN + 7) / 8, 256, 0, stream>>>(h1b, w1, wself1, rowptr_n, csr_src,
                                                b1, agg1b, NN, H, C1);

  // ---- conv2 (single pass): GEMM (+fused e) -> alpha -> fused aggregate+pool ----
  {
    dim3 gg(HC2 / 128, (NN + 127) / 128);
    gemm_mfma<128><<<gg, 256, 0, stream>>>(agg1b, W2T, h2b, NN, HC2, HC1,
                                           a_src2, a_dst2, es2, ed2, H);
  }
  alpha_kernel<<<(NN * H + 255) / 256, 256, 0, stream>>>(es2, ed2, rowptr_n, csr_src,
                                                         w2, wself2, NN, H);
  agg_pool<<<G, 256, 0, stream>>>(h2b, w2, wself2, rowptr_n, csr_src, b2, rowptr_g, zb);

  // ---- head ----
  {
    dim3 gg(KS_Z, G / 128);
    gemm_mfma_n64<<<gg, 256, 0, stream>>>(zb, KZ, Wfc1T, KZ, Cp_z, G, KZ / KS_Z);
    mlp_finish<<<G, 64, 0, stream>>>(Cp_z, KS_Z, G, bfc1, Wfc2, bfc2, out);
  }
}

// Round 10
// 516.224 us; speedup vs baseline: 3.5632x; 1.0091x over previous
//
#include <hip/hip_runtime.h>
#include <math.h>

#define NEG_SLOPE 0.2f

typedef __attribute__((ext_vector_type(8))) short bf16x8;   // 8 bf16 (4 VGPRs)
typedef __attribute__((ext_vector_type(4))) float f32x4;    // MFMA acc

__device__ __forceinline__ float b2f(short s) {
  return __uint_as_float(((unsigned int)(unsigned short)s) << 16);
}
__device__ __forceinline__ unsigned short f2b_rne(float f) {
  unsigned int u = __float_as_uint(f);
  u = (u + 0x7FFF + ((u >> 16) & 1)) >> 16;
  return (unsigned short)u;
}

// ---------------- fp32 -> bf16 elementwise ----------------
__global__ void cvt_f2b(const float* __restrict__ in, unsigned short* __restrict__ out, size_t n)
{
  size_t i = (size_t)blockIdx.x * 256 + threadIdx.x;
  size_t stride = (size_t)gridDim.x * 256;
  for (; i < n; i += stride) out[i] = f2b_rne(in[i]);
}

// ---------------- W [K,N] f32 -> WT [N,K] bf16 ----------------
__global__ void transpose_f2b(const float* __restrict__ W, unsigned short* __restrict__ WT,
                              int K, int N)
{
  int idx = blockIdx.x * 256 + threadIdx.x;
  if (idx < K * N) {
    int k = idx / N, n = idx - k * N;
    WT[(size_t)n * K + k] = f2b_rne(W[idx]);
  }
}

// ---------------- MFMA GEMM + fused e epilogue, register-prefetch dbuf ----------------
template<int EMODE>
__global__ __launch_bounds__(256) void gemm_mfma(
    const unsigned short* __restrict__ A, const unsigned short* __restrict__ BT,
    unsigned short* __restrict__ Cout, int M, int N, int K,
    const float* __restrict__ a_src, const float* __restrict__ a_dst,
    float* __restrict__ es, float* __restrict__ ed, int nh)
{
  const int LDT = 40;
  __shared__ unsigned short As[128 * 40];
  __shared__ unsigned short Bs[128 * 40];
  const int tid  = threadIdx.x;
  const int wave = tid >> 6;
  const int lane = tid & 63;
  const int ln   = lane & 15;
  const int quad = lane >> 4;
  const int wr0  = (wave >> 1) * 64;
  const int wc0  = (wave & 1) * 64;
  const int bm   = blockIdx.y * 128;
  const int bn   = blockIdx.x * 128;
  const int srow  = tid >> 2;
  const int skoff = (tid & 3) * 8;

  f32x4 acc[4][4];
  const f32x4 z4 = {0.f, 0.f, 0.f, 0.f};
#pragma unroll
  for (int i = 0; i < 4; ++i)
#pragma unroll
    for (int j = 0; j < 4; ++j) acc[i][j] = z4;

  const bf16x8 zb8 = {0, 0, 0, 0, 0, 0, 0, 0};
  bf16x8 pa[2] = {zb8, zb8}, pb[2] = {zb8, zb8};
  bf16x8 na[2] = {zb8, zb8}, nb[2] = {zb8, zb8};
#pragma unroll
  for (int p = 0; p < 2; ++p) {
    int r = srow + p * 64;
    pa[p] = (bm + r < M) ? *(const bf16x8*)(A + (size_t)(bm + r) * K + skoff) : zb8;
    pb[p] = *(const bf16x8*)(BT + (size_t)(bn + r) * K + skoff);
  }

  for (int k0 = 0; k0 < K; k0 += 32) {
#pragma unroll
    for (int p = 0; p < 2; ++p) {
      int r = srow + p * 64;
      *(bf16x8*)(&As[r * LDT + skoff]) = pa[p];
      *(bf16x8*)(&Bs[r * LDT + skoff]) = pb[p];
    }
    __syncthreads();
    if (k0 + 32 < K) {
      int kn = k0 + 32;
#pragma unroll
      for (int p = 0; p < 2; ++p) {
        int r = srow + p * 64;
        na[p] = (bm + r < M) ? *(const bf16x8*)(A + (size_t)(bm + r) * K + kn + skoff) : zb8;
        nb[p] = *(const bf16x8*)(BT + (size_t)(bn + r) * K + kn + skoff);
      }
    }
    bf16x8 af[4], bfv[4];
#pragma unroll
    for (int i = 0; i < 4; ++i)
      af[i] = *(const bf16x8*)(&As[(wr0 + i * 16 + ln) * LDT + quad * 8]);
#pragma unroll
    for (int j = 0; j < 4; ++j)
      bfv[j] = *(const bf16x8*)(&Bs[(wc0 + j * 16 + ln) * LDT + quad * 8]);
#pragma unroll
    for (int i = 0; i < 4; ++i)
#pragma unroll
      for (int j = 0; j < 4; ++j)
        acc[i][j] = __builtin_amdgcn_mfma_f32_16x16x32_bf16(af[i], bfv[j], acc[i][j], 0, 0, 0);
    __syncthreads();
#pragma unroll
    for (int p = 0; p < 2; ++p) { pa[p] = na[p]; pb[p] = nb[p]; }
  }

#pragma unroll
  for (int i = 0; i < 4; ++i) {
#pragma unroll
    for (int r = 0; r < 4; ++r) {
      int row = bm + wr0 + i * 16 + quad * 4 + r;
      if (row >= M) continue;
#pragma unroll
      for (int j = 0; j < 4; ++j) {
        int col = bn + wc0 + j * 16 + ln;
        Cout[(size_t)row * N + col] = f2b_rne(acc[i][j][r]);
      }
    }
  }

  float asv[4], adv[4];
#pragma unroll
  for (int j = 0; j < 4; ++j) {
    int col = bn + wc0 + j * 16 + ln;
    asv[j] = a_src[col];
    adv[j] = a_dst[col];
  }
  if (EMODE == 64) {
    const int head = (bn + wc0) >> 6;
#pragma unroll
    for (int i = 0; i < 4; ++i) {
#pragma unroll
      for (int r = 0; r < 4; ++r) {
        float ps = 0.f, pd = 0.f;
#pragma unroll
        for (int j = 0; j < 4; ++j) {
          ps = fmaf(acc[i][j][r], asv[j], ps);
          pd = fmaf(acc[i][j][r], adv[j], pd);
        }
        for (int off = 8; off; off >>= 1) {
          ps += __shfl_down(ps, off, 16);
          pd += __shfl_down(pd, off, 16);
        }
        if (ln == 0) {
          int row = bm + wr0 + i * 16 + quad * 4 + r;
          if (row < M) {
            es[(size_t)row * nh + head] = ps;
            ed[(size_t)row * nh + head] = pd;
          }
        }
      }
    }
  } else {
    float* esp = (float*)As;
    float* edp = esp + 256;
#pragma unroll
    for (int i = 0; i < 4; ++i) {
#pragma unroll
      for (int r = 0; r < 4; ++r) {
        float ps = 0.f, pd = 0.f;
#pragma unroll
        for (int j = 0; j < 4; ++j) {
          ps = fmaf(acc[i][j][r], asv[j], ps);
          pd = fmaf(acc[i][j][r], adv[j], pd);
        }
        for (int off = 8; off; off >>= 1) {
          ps += __shfl_down(ps, off, 16);
          pd += __shfl_down(pd, off, 16);
        }
        if (ln == 0) {
          int rl = wr0 + i * 16 + quad * 4 + r;
          esp[rl * 2 + (wc0 >> 6)] = ps;
          edp[rl * 2 + (wc0 >> 6)] = pd;
        }
      }
    }
    __syncthreads();
    if (tid < 128) {
      int row = bm + tid;
      if (row < M) {
        int head = bn >> 7;
        es[(size_t)row * nh + head] = esp[tid * 2] + esp[tid * 2 + 1];
        ed[(size_t)row * nh + head] = edp[tid * 2] + edp[tid * 2 + 1];
      }
    }
  }
}

// ---------------- skinny MFMA GEMM, N=64, split-K, fp32 partials ----------------
__global__ __launch_bounds__(256) void gemm_mfma_n64(
    const unsigned short* __restrict__ A, int lda,
    const unsigned short* __restrict__ BT, int ldb,
    float* __restrict__ Cp, int M, int kchunk)
{
  const int LDT = 72;
  __shared__ unsigned short As[128 * 72];
  __shared__ unsigned short Bs[64 * 72];
  const int tid  = threadIdx.x;
  const int wave = tid >> 6;
  const int lane = tid & 63;
  const int ln   = lane & 15;
  const int quad = lane >> 4;
  const int ks   = blockIdx.x;
  const int bm   = blockIdx.y * 128;
  const int k_beg = ks * kchunk;
  const int k_end = k_beg + kchunk;
  const int arow = tid >> 1;
  const int akb  = (tid & 1) * 32;
  const int brow = tid >> 2;
  const int bkb  = (tid & 3) * 16;

  f32x4 acc[2][4];
  const f32x4 z4 = {0.f, 0.f, 0.f, 0.f};
#pragma unroll
  for (int i = 0; i < 2; ++i)
#pragma unroll
    for (int j = 0; j < 4; ++j) acc[i][j] = z4;

  for (int k0 = k_beg; k0 < k_end; k0 += 64) {
    const unsigned short* ap = A + (size_t)(bm + arow) * lda + k0 + akb;
#pragma unroll
    for (int q = 0; q < 4; ++q)
      *(bf16x8*)(&As[arow * LDT + akb + q * 8]) = *(const bf16x8*)(ap + q * 8);
    const unsigned short* bp = BT + (size_t)brow * ldb + k0 + bkb;
#pragma unroll
    for (int q = 0; q < 2; ++q)
      *(bf16x8*)(&Bs[brow * LDT + bkb + q * 8]) = *(const bf16x8*)(bp + q * 8);
    __syncthreads();
#pragma unroll
    for (int kk = 0; kk < 2; ++kk) {
      bf16x8 af[2], bfv[4];
#pragma unroll
      for (int i = 0; i < 2; ++i)
        af[i] = *(const bf16x8*)(&As[(wave * 32 + i * 16 + ln) * LDT + kk * 32 + quad * 8]);
#pragma unroll
      for (int j = 0; j < 4; ++j)
        bfv[j] = *(const bf16x8*)(&Bs[(j * 16 + ln) * LDT + kk * 32 + quad * 8]);
#pragma unroll
      for (int i = 0; i < 2; ++i)
#pragma unroll
        for (int j = 0; j < 4; ++j)
          acc[i][j] = __builtin_amdgcn_mfma_f32_16x16x32_bf16(af[i], bfv[j], acc[i][j], 0, 0, 0);
    }
    __syncthreads();
  }
#pragma unroll
  for (int i = 0; i < 2; ++i)
#pragma unroll
    for (int r = 0; r < 4; ++r) {
      int row = bm + wave * 32 + i * 16 + quad * 4 + r;
#pragma unroll
      for (int j = 0; j < 4; ++j)
        Cp[((size_t)ks * M + row) * 64 + j * 16 + ln] = acc[i][j][r];
    }
}

// ---------------- fp partial reduce + bias -> bf16 into z cols [512,576) ----------------
__global__ void fp_finish(const float* __restrict__ Cp, int ksplit, int M,
                          const float* __restrict__ bfp,
                          unsigned short* __restrict__ zb)
{
  const int g = blockIdx.x;
  const int j = threadIdx.x;
  float s = bfp[j];
  for (int ks = 0; ks < ksplit; ++ks) s += Cp[((size_t)ks * M + g) * 64 + j];
  zb[(size_t)g * 576 + 512 + j] = f2b_rne(s);
}

// ---------------- mlp partial reduce + bias + relu + fc2 dot -> out ----------------
__global__ void mlp_finish(const float* __restrict__ Cp, int ksplit, int M,
                           const float* __restrict__ bfc1,
                           const float* __restrict__ Wfc2, const float* __restrict__ bfc2,
                           float* __restrict__ out)
{
  const int g = blockIdx.x;
  const int j = threadIdx.x;
  float s = bfc1[j];
  for (int ks = 0; ks < ksplit; ++ks) s += Cp[((size_t)ks * M + g) * 64 + j];
  s = s > 0.f ? s : 0.f;
  float term = s * Wfc2[j];
  for (int off = 32; off; off >>= 1) term += __shfl_down(term, off, 64);
  if (j == 0) out[g] = term + bfc2[0];
}

// ---------------- CSR build ----------------
__global__ void count_deg(const int* __restrict__ ei, int E, int* __restrict__ deg)
{
  int e = blockIdx.x * 256 + threadIdx.x;
  if (e < E) atomicAdd(&deg[ei[E + e]], 1);
}

__global__ void fill_csr(const int* __restrict__ ei, int E, int* __restrict__ cursor,
                         const int* __restrict__ rowptr, int* __restrict__ csr_src)
{
  int e = blockIdx.x * 256 + threadIdx.x;
  if (e < E) {
    int d = ei[E + e];
    int pos = atomicAdd(&cursor[d], 1);
    csr_src[rowptr[d] + pos] = ei[e];
  }
}

__global__ void count_graph(const int* __restrict__ batch, int N, int* __restrict__ gcnt)
{
  int i = blockIdx.x * 256 + threadIdx.x;
  if (i < N) atomicAdd(&gcnt[batch[i]], 1);
}

// ---------------- 3-phase exclusive scan ----------------
__global__ void scan_p1(const int* __restrict__ vals, int n, int* __restrict__ bsum)
{
  __shared__ int red[256];
  int base = blockIdx.x * 1024;
  int t = threadIdx.x;
  int s = 0;
#pragma unroll
  for (int i = 0; i < 4; ++i) {
    int idx = base + i * 256 + t;
    if (idx < n) s += vals[idx];
  }
  red[t] = s;
  __syncthreads();
  for (int off = 128; off; off >>= 1) {
    if (t < off) red[t] += red[t + off];
    __syncthreads();
  }
  if (t == 0) bsum[blockIdx.x] = red[0];
}

__global__ void scan_p2(const int* __restrict__ bsum, int* __restrict__ bpre,
                        int nb, int* __restrict__ rowptr, int n)
{
  __shared__ int tmp[128];
  int t = threadIdx.x;
  int v = (t < nb) ? bsum[t] : 0;
  tmp[t] = v;
  __syncthreads();
  for (int off = 1; off < 128; off <<= 1) {
    int add = (t >= off) ? tmp[t - off] : 0;
    __syncthreads();
    tmp[t] += add;
    __syncthreads();
  }
  if (t < nb) bpre[t] = tmp[t] - v;
  if (t == 127) rowptr[n] = tmp[127];
}

__global__ void scan_p3(const int* __restrict__ vals, const int* __restrict__ bpre,
                        int n, int* __restrict__ rowptr)
{
  __shared__ int tmp[256];
  int t = threadIdx.x;
  int base = blockIdx.x * 1024 + t * 4;
  int v[4]; int s = 0;
#pragma unroll
  for (int i = 0; i < 4; ++i) {
    int idx = base + i;
    v[i] = (idx < n) ? vals[idx] : 0;
    s += v[i];
  }
  tmp[t] = s;
  __syncthreads();
  for (int off = 1; off < 256; off <<= 1) {
    int add = (t >= off) ? tmp[t - off] : 0;
    __syncthreads();
    tmp[t] += add;
    __syncthreads();
  }
  int run = bpre[blockIdx.x] + tmp[t] - s;
#pragma unroll
  for (int i = 0; i < 4; ++i) {
    int idx = base + i;
    if (idx < n) rowptr[idx] = run;
    run += v[i];
  }
}

// ---------------- attention weights, ONE pass: unnormalized w + dinv ----------------
__global__ void alpha_kernel(const float* __restrict__ es, const float* __restrict__ ed,
                             const int* __restrict__ rowptr, const int* __restrict__ csr_src,
                             float* __restrict__ w_csr, float* __restrict__ wself,
                             float* __restrict__ dinv, int N, int nh)
{
  int idx = blockIdx.x * 256 + threadIdx.x;
  if (idx >= N * nh) return;
  const int dst = idx / nh;
  const int h = idx - dst * nh;
  const float edh = ed[(size_t)dst * nh + h];
  const int beg = rowptr[dst], end = rowptr[dst + 1];
  float sum = 0.f;
  for (int e = beg; e < end; ++e) {
    int s = csr_src[e];
    float l = es[(size_t)s * nh + h] + edh;
    l = l >= 0.f ? l : NEG_SLOPE * l;
    float w = expf(l);
    w_csr[(size_t)e * nh + h] = w;
    sum += w;
  }
  float ls = es[(size_t)dst * nh + h] + edh;
  ls = ls >= 0.f ? ls : NEG_SLOPE * ls;
  float wsl = expf(ls);
  sum += wsl;
  wself[(size_t)dst * nh + h] = wsl;
  dinv[(size_t)dst * nh + h] = 1.0f / sum;
}

// ---------------- conv1 aggregate, channel-SLICED (2 slices of 128 ch) ----------------
// grid = ((N+15)/16, 2). Each block: 16 dsts x 128 channels. 16 lanes/dst x 8ch.
// Scales by dinv at the end (w unnormalized).
__global__ __launch_bounds__(256) void aggregate_b(
    const unsigned short* __restrict__ h,
    const float* __restrict__ w_csr, const float* __restrict__ wself,
    const float* __restrict__ dinv,
    const int* __restrict__ rowptr, const int* __restrict__ csr_src,
    const float* __restrict__ bias, unsigned short* __restrict__ out, int N)
{
  const int HC = 256;
  const int p = blockIdx.y;                 // slice
  const int grp = threadIdx.x >> 4;         // 0..15 dst within block
  const int l16 = threadIdx.x & 15;
  const int dst = blockIdx.x * 16 + grp;
  if (dst >= N) return;
  const int ch = p * 128 + l16 * 8;
  const int head = ch >> 6;                 // C1=64
  const int beg = rowptr[dst], end = rowptr[dst + 1];
  float acc[8] = {0.f, 0.f, 0.f, 0.f, 0.f, 0.f, 0.f, 0.f};
  int e = beg;
  for (; e + 1 < end; e += 2) {
    int s0 = csr_src[e], s1 = csr_src[e + 1];
    float a0 = w_csr[(size_t)e * 4 + head];
    float a1 = w_csr[(size_t)(e + 1) * 4 + head];
    bf16x8 h0 = *(const bf16x8*)(h + (size_t)s0 * HC + ch);
    bf16x8 h1 = *(const bf16x8*)(h + (size_t)s1 * HC + ch);
#pragma unroll
    for (int r = 0; r < 8; ++r) acc[r] = fmaf(a0, b2f(h0[r]), acc[r]);
#pragma unroll
    for (int r = 0; r < 8; ++r) acc[r] = fmaf(a1, b2f(h1[r]), acc[r]);
  }
  if (e < end) {
    int s0 = csr_src[e];
    float a0 = w_csr[(size_t)e * 4 + head];
    bf16x8 h0 = *(const bf16x8*)(h + (size_t)s0 * HC + ch);
#pragma unroll
    for (int r = 0; r < 8; ++r) acc[r] = fmaf(a0, b2f(h0[r]), acc[r]);
  }
  {
    float a = wself[(size_t)dst * 4 + head];
    bf16x8 hv = *(const bf16x8*)(h + (size_t)dst * HC + ch);
#pragma unroll
    for (int r = 0; r < 8; ++r) acc[r] = fmaf(a, b2f(hv[r]), acc[r]);
  }
  const float di = dinv[(size_t)dst * 4 + head];
  bf16x8 o;
#pragma unroll
  for (int r = 0; r < 8; ++r) {
    float v = acc[r] * di + bias[ch + r];
    v = v > 0.f ? v : (expf(v) - 1.0f);
    o[r] = (short)f2b_rne(v);
  }
  *(bf16x8*)(out + (size_t)dst * HC + ch) = o;
}

// ---------------- conv2 aggregate + ELU + mean-pool, channel-SLICED ----------------
// grid = (G, 2). Each block: one graph x 256 channels (slice p).
// 32 lanes x 8ch per node; 2 nodes/wave; 8 nodes in flight. No atomics.
__global__ __launch_bounds__(256) void agg_pool(
    const unsigned short* __restrict__ h,
    const float* __restrict__ w_csr, const float* __restrict__ wself,
    const float* __restrict__ dinv,
    const int* __restrict__ rowptr, const int* __restrict__ csr_src,
    const float* __restrict__ bias, const int* __restrict__ grp,
    unsigned short* __restrict__ zb)
{
  const int g = blockIdx.x;
  const int p = blockIdx.y;                 // slice: channels [p*256, p*256+256)
  const int wave = threadIdx.x >> 6;
  const int lane = threadIdx.x & 63;
  const int lg   = lane >> 5;               // node subgroup (0/1)
  const int ll   = lane & 31;
  const int ch   = p * 256 + ll * 8;        // global channel
  const int head = ch >> 7;                 // C2=128
  const int slot = wave * 2 + lg;           // 0..7
  const int gbeg = grp[g], gend = grp[g + 1];
  float bch[8];
#pragma unroll
  for (int r = 0; r < 8; ++r) bch[r] = bias[ch + r];
  float pool[8] = {0.f, 0.f, 0.f, 0.f, 0.f, 0.f, 0.f, 0.f};

  for (int node = gbeg + slot; node < gend; node += 8) {
    const int beg = rowptr[node], end = rowptr[node + 1];
    float acc[8] = {0.f, 0.f, 0.f, 0.f, 0.f, 0.f, 0.f, 0.f};
    int e = beg;
    for (; e + 1 < end; e += 2) {
      int s0 = csr_src[e], s1 = csr_src[e + 1];
      float a0 = w_csr[(size_t)e * 4 + head];
      float a1 = w_csr[(size_t)(e + 1) * 4 + head];
      bf16x8 h0 = *(const bf16x8*)(h + (size_t)s0 * 512 + ch);
      bf16x8 h1 = *(const bf16x8*)(h + (size_t)s1 * 512 + ch);
#pragma unroll
      for (int r = 0; r < 8; ++r) acc[r] = fmaf(a0, b2f(h0[r]), acc[r]);
#pragma unroll
      for (int r = 0; r < 8; ++r) acc[r] = fmaf(a1, b2f(h1[r]), acc[r]);
    }
    if (e < end) {
      int s0 = csr_src[e];
      float a0 = w_csr[(size_t)e * 4 + head];
      bf16x8 h0 = *(const bf16x8*)(h + (size_t)s0 * 512 + ch);
#pragma unroll
      for (int r = 0; r < 8; ++r) acc[r] = fmaf(a0, b2f(h0[r]), acc[r]);
    }
    {
      float a = wself[(size_t)node * 4 + head];
      bf16x8 hv = *(const bf16x8*)(h + (size_t)node * 512 + ch);
#pragma unroll
      for (int r = 0; r < 8; ++r) acc[r] = fmaf(a, b2f(hv[r]), acc[r]);
    }
    const float di = dinv[(size_t)node * 4 + head];
#pragma unroll
    for (int r = 0; r < 8; ++r) {
      float v = acc[r] * di + bch[r];
      v = v > 0.f ? v : (expf(v) - 1.0f);   // ELU
      pool[r] += v;
    }
  }

  __shared__ float red[8][256];
#pragma unroll
  for (int r = 0; r < 8; ++r) red[slot][ll * 8 + r] = pool[r];
  __syncthreads();
  const float inv = 1.0f / (float)max(gend - gbeg, 1);
  {
    int c = threadIdx.x;  // 0..255 channel within slice
    float s = ((red[0][c] + red[1][c]) + (red[2][c] + red[3][c]))
            + ((red[4][c] + red[5][c]) + (red[6][c] + red[7][c]));
    zb[(size_t)g * 576 + p * 256 + c] = f2b_rne(s * inv);
  }
}

// ---------------- launcher ----------------
extern "C" void kernel_launch(void* const* d_in, const int* in_sizes, int n_in,
                              void* d_out, int out_size, void* d_ws, size_t ws_size,
                              hipStream_t stream)
{
  const float* x      = (const float*)d_in[0];
  const int*   ei     = (const int*)d_in[1];
  const int*   batch  = (const int*)d_in[2];
  const float* fp     = (const float*)d_in[3];
  const float* W1     = (const float*)d_in[4];
  const float* a_src1 = (const float*)d_in[5];
  const float* a_dst1 = (const float*)d_in[6];
  const float* b1     = (const float*)d_in[7];
  const float* W2     = (const float*)d_in[8];
  const float* a_src2 = (const float*)d_in[9];
  const float* a_dst2 = (const float*)d_in[10];
  const float* b2     = (const float*)d_in[11];
  const float* Wfp    = (const float*)d_in[12];
  const float* bfp    = (const float*)d_in[13];
  const float* Wfc1   = (const float*)d_in[14];
  const float* bfc1   = (const float*)d_in[15];
  const float* Wfc2   = (const float*)d_in[16];
  const float* bfc2   = (const float*)d_in[17];
  float* out = (float*)d_out;

  const int NN = in_sizes[0] / 128;
  const int E  = in_sizes[1] / 2;
  const int G  = in_sizes[3] / 2048;
  const int FIN = 128, H = 4, C1 = 64, C2 = 128;
  const int HC1 = H * C1;   // 256
  const int HC2 = H * C2;   // 512
  const int KFP = in_sizes[3] / G;   // 2048
  const int KZ  = HC2 + 64;          // 576
  const int KS_FP = 16;
  const int KS_Z  = 9;

  // ---- workspace: liverange-overlaid regions ----
  char* base = (char*)d_ws;
  size_t off = 0;
  auto alloc = [&](size_t bytes) {
    char* p = base + off; off += (bytes + 255) & ~(size_t)255; return p;
  };
  // Region A: early xb+h1b; late h2b
  size_t xb_sz  = ((size_t)NN * FIN * 2 + 255) & ~(size_t)255;
  size_t h1b_sz = (size_t)NN * HC1 * 2;
  size_t h2b_sz = (size_t)NN * HC2 * 2;
  size_t rA = xb_sz + h1b_sz; if (h2b_sz > rA) rA = h2b_sz;
  char* RA = alloc(rA);
  unsigned short* xb  = (unsigned short*)RA;
  unsigned short* h1b = (unsigned short*)(RA + xb_sz);
  unsigned short* h2b = (unsigned short*)RA;
  // Region B: early fpb+Cp_fp; late agg1b
  size_t fpb_sz  = ((size_t)G * KFP * 2 + 255) & ~(size_t)255;
  size_t cpfp_sz = (size_t)KS_FP * G * 64 * 4;
  size_t agg1_sz = (size_t)NN * HC1 * 2;
  size_t rB = fpb_sz + cpfp_sz; if (agg1_sz > rB) rB = agg1_sz;
  char* RB = alloc(rB);
  unsigned short* fpb   = (unsigned short*)RB;
  float*          Cp_fp = (float*)(RB + fpb_sz);
  unsigned short* agg1b = (unsigned short*)RB;
  // Region C: attn buffers (shared by conv1/conv2 sequentially)
  float* w1     = (float*)alloc((size_t)E * H * 4);
  float* wself1 = (float*)alloc((size_t)NN * H * 4);
  float* es1    = (float*)alloc((size_t)NN * H * 4);
  float* ed1    = (float*)alloc((size_t)NN * H * 4);
  float* dinv1  = (float*)alloc((size_t)NN * H * 4);
  float* w2 = w1, *wself2 = wself1, *es2 = es1, *ed2 = ed1, *dinv2 = dinv1;
  // Persistent small buffers
  unsigned short* zb    = (unsigned short*)alloc((size_t)G * KZ * 2);
  float*          Cp_z  = (float*)alloc((size_t)KS_Z * G * 64 * 4);
  unsigned short* W1T   = (unsigned short*)alloc((size_t)HC1 * FIN * 2);
  unsigned short* W2T   = (unsigned short*)alloc((size_t)HC2 * HC1 * 2);
  unsigned short* WfpT  = (unsigned short*)alloc((size_t)64 * KFP * 2);
  unsigned short* Wfc1T = (unsigned short*)alloc((size_t)64 * KZ * 2);
  // int arena: deg/cursor/gcnt contiguous (single memset)
  int* iarena   = (int*)alloc(((size_t)2 * NN + G) * 4);
  int* deg      = iarena;
  int* cursor   = iarena + NN;
  int* gcnt     = iarena + 2 * NN;
  int* rowptr_n = (int*)alloc(((size_t)NN + 1) * 4);
  int* rowptr_g = (int*)alloc(((size_t)G + 1) * 4);
  int* csr_src  = (int*)alloc((size_t)E * 4);
  int* bsum     = (int*)alloc(128 * 4);
  int* bpre     = (int*)alloc(128 * 4);

  // ---- conversions ----
  {
    size_t nx = (size_t)NN * FIN;
    cvt_f2b<<<(int)((nx + 255) / 256), 256, 0, stream>>>(x, xb, nx);
    size_t nf = (size_t)G * KFP;
    cvt_f2b<<<2048, 256, 0, stream>>>(fp, fpb, nf);
    transpose_f2b<<<(FIN * HC1 + 255) / 256, 256, 0, stream>>>(W1, W1T, FIN, HC1);
    transpose_f2b<<<(HC1 * HC2 + 255) / 256, 256, 0, stream>>>(W2, W2T, HC1, HC2);
    transpose_f2b<<<(KFP * 64 + 255) / 256, 256, 0, stream>>>(Wfp, WfpT, KFP, 64);
    transpose_f2b<<<(KZ * 64 + 255) / 256, 256, 0, stream>>>(Wfc1, Wfc1T, KZ, 64);
  }

  // ---- fingerprint branch ----
  {
    dim3 gg(KS_FP, G / 128);
    gemm_mfma_n64<<<gg, 256, 0, stream>>>(fpb, KFP, WfpT, KFP, Cp_fp, G, KFP / KS_FP);
    fp_finish<<<G, 64, 0, stream>>>(Cp_fp, KS_FP, G, bfp, zb);
  }

  // ---- CSR by dst + graph segment ptrs ----
  hipMemsetAsync(iarena, 0, sizeof(int) * ((size_t)2 * NN + G), stream);
  count_deg<<<(E + 255) / 256, 256, 0, stream>>>(ei, E, deg);
  {
    int nb = (NN + 1023) / 1024;
    scan_p1<<<nb, 256, 0, stream>>>(deg, NN, bsum);
    scan_p2<<<1, 128, 0, stream>>>(bsum, bpre, nb, rowptr_n, NN);
    scan_p3<<<nb, 256, 0, stream>>>(deg, bpre, NN, rowptr_n);
  }
  fill_csr<<<(E + 255) / 256, 256, 0, stream>>>(ei, E, cursor, rowptr_n, csr_src);
  count_graph<<<(NN + 255) / 256, 256, 0, stream>>>(batch, NN, gcnt);
  {
    int nb = (G + 1023) / 1024;
    scan_p1<<<nb, 256, 0, stream>>>(gcnt, G, bsum);
    scan_p2<<<1, 128, 0, stream>>>(bsum, bpre, nb, rowptr_g, G);
    scan_p3<<<nb, 256, 0, stream>>>(gcnt, bpre, G, rowptr_g);
  }

  // ---- conv1: GEMM (+fused e) -> alpha -> sliced aggregate ----
  {
    dim3 gg(HC1 / 128, (NN + 127) / 128);
    gemm_mfma<64><<<gg, 256, 0, stream>>>(xb, W1T, h1b, NN, HC1, FIN,
                                          a_src1, a_dst1, es1, ed1, H);
  }
  alpha_kernel<<<(NN * H + 255) / 256, 256, 0, stream>>>(es1, ed1, rowptr_n, csr_src,
                                                         w1, wself1, dinv1, NN, H);
  {
    dim3 gg((NN + 15) / 16, 2);
    aggregate_b<<<gg, 256, 0, stream>>>(h1b, w1, wself1, dinv1, rowptr_n, csr_src,
                                        b1, agg1b, NN);
  }

  // ---- conv2: GEMM (+fused e) -> alpha -> sliced fused aggregate+pool ----
  {
    dim3 gg(HC2 / 128, (NN + 127) / 128);
    gemm_mfma<128><<<gg, 256, 0, stream>>>(agg1b, W2T, h2b, NN, HC2, HC1,
                                           a_src2, a_dst2, es2, ed2, H);
  }
  alpha_kernel<<<(NN * H + 255) / 256, 256, 0, stream>>>(es2, ed2, rowptr_n, csr_src,
                                                         w2, wself2, dinv2, NN, H);
  {
    dim3 gg(G, 2);
    agg_pool<<<gg, 256, 0, stream>>>(h2b, w2, wself2, dinv2, rowptr_n, csr_src,
                                     b2, rowptr_g, zb);
  }

  // ---- head ----
  {
    dim3 gg(KS_Z, G / 128);
    gemm_mfma_n64<<<gg, 256, 0, stream>>>(zb, KZ, Wfc1T, KZ, Cp_z, G, KZ / KS_Z);
    mlp_finish<<<G, 64, 0, stream>>>(Cp_z, KS_Z, G, bfc1, Wfc2, bfc2, out);
  }
}

// Round 11
// 492.264 us; speedup vs baseline: 3.7367x; 1.0487x over previous
//
#include <hip/hip_runtime.h>
#include <math.h>

#define NEG_SLOPE 0.2f

typedef __attribute__((ext_vector_type(8))) short bf16x8;   // 8 bf16 (4 VGPRs)
typedef __attribute__((ext_vector_type(4))) float f32x4;    // MFMA acc

__device__ __forceinline__ float b2f(short s) {
  return __uint_as_float(((unsigned int)(unsigned short)s) << 16);
}
__device__ __forceinline__ unsigned short f2b_rne(float f) {
  unsigned int u = __float_as_uint(f);
  u = (u + 0x7FFF + ((u >> 16) & 1)) >> 16;
  return (unsigned short)u;
}

// ---------------- fused prep: cvt x, cvt fp, 4 weight transposes ----------------
__device__ __forceinline__ void tr_one(const float* __restrict__ W,
                                       unsigned short* __restrict__ WT,
                                       int K, int N, int idx)
{
  if (idx < K * N) {
    int k = idx / N, n = idx - k * N;
    WT[(size_t)n * K + k] = f2b_rne(W[idx]);
  }
}

__global__ __launch_bounds__(256) void prep_all(
    const float* __restrict__ x, unsigned short* __restrict__ xb, size_t nx, int B0,
    const float* __restrict__ fp, unsigned short* __restrict__ fpb, size_t nf, int B1,
    const float* __restrict__ W1, unsigned short* __restrict__ W1T,
    const float* __restrict__ W2, unsigned short* __restrict__ W2T,
    const float* __restrict__ Wfp, unsigned short* __restrict__ WfpT,
    const float* __restrict__ Wfc1, unsigned short* __restrict__ Wfc1T)
{
  int b = blockIdx.x;
  const int t = threadIdx.x;
  if (b < B0) {
    size_t i = (size_t)b * 256 + t;
    if (i < nx) xb[i] = f2b_rne(x[i]);
    return;
  }
  b -= B0;
  if (b < B1) {
    size_t i = (size_t)b * 256 + t;
    if (i < nf) fpb[i] = f2b_rne(fp[i]);
    return;
  }
  b -= B1;
  if (b < 128) { tr_one(W1, W1T, 128, 256, b * 256 + t); return; }
  b -= 128;
  if (b < 512) { tr_one(W2, W2T, 256, 512, b * 256 + t); return; }
  b -= 512;
  if (b < 512) { tr_one(Wfp, WfpT, 2048, 64, b * 256 + t); return; }
  b -= 512;
  tr_one(Wfc1, Wfc1T, 576, 64, b * 256 + t);
}

// ---------------- MFMA GEMM + fused e epilogue, register-prefetch dbuf ----------------
template<int EMODE>
__global__ __launch_bounds__(256) void gemm_mfma(
    const unsigned short* __restrict__ A, const unsigned short* __restrict__ BT,
    unsigned short* __restrict__ Cout, int M, int N, int K,
    const float* __restrict__ a_src, const float* __restrict__ a_dst,
    float* __restrict__ es, float* __restrict__ ed, int nh)
{
  const int LDT = 40;
  __shared__ unsigned short As[128 * 40];
  __shared__ unsigned short Bs[128 * 40];
  const int tid  = threadIdx.x;
  const int wave = tid >> 6;
  const int lane = tid & 63;
  const int ln   = lane & 15;
  const int quad = lane >> 4;
  const int wr0  = (wave >> 1) * 64;
  const int wc0  = (wave & 1) * 64;
  const int bm   = blockIdx.y * 128;
  const int bn   = blockIdx.x * 128;
  const int srow  = tid >> 2;
  const int skoff = (tid & 3) * 8;

  f32x4 acc[4][4];
  const f32x4 z4 = {0.f, 0.f, 0.f, 0.f};
#pragma unroll
  for (int i = 0; i < 4; ++i)
#pragma unroll
    for (int j = 0; j < 4; ++j) acc[i][j] = z4;

  const bf16x8 zb8 = {0, 0, 0, 0, 0, 0, 0, 0};
  bf16x8 pa[2] = {zb8, zb8}, pb[2] = {zb8, zb8};
  bf16x8 na[2] = {zb8, zb8}, nb[2] = {zb8, zb8};
#pragma unroll
  for (int p = 0; p < 2; ++p) {
    int r = srow + p * 64;
    pa[p] = (bm + r < M) ? *(const bf16x8*)(A + (size_t)(bm + r) * K + skoff) : zb8;
    pb[p] = *(const bf16x8*)(BT + (size_t)(bn + r) * K + skoff);
  }

  for (int k0 = 0; k0 < K; k0 += 32) {
#pragma unroll
    for (int p = 0; p < 2; ++p) {
      int r = srow + p * 64;
      *(bf16x8*)(&As[r * LDT + skoff]) = pa[p];
      *(bf16x8*)(&Bs[r * LDT + skoff]) = pb[p];
    }
    __syncthreads();
    if (k0 + 32 < K) {
      int kn = k0 + 32;
#pragma unroll
      for (int p = 0; p < 2; ++p) {
        int r = srow + p * 64;
        na[p] = (bm + r < M) ? *(const bf16x8*)(A + (size_t)(bm + r) * K + kn + skoff) : zb8;
        nb[p] = *(const bf16x8*)(BT + (size_t)(bn + r) * K + kn + skoff);
      }
    }
    bf16x8 af[4], bfv[4];
#pragma unroll
    for (int i = 0; i < 4; ++i)
      af[i] = *(const bf16x8*)(&As[(wr0 + i * 16 + ln) * LDT + quad * 8]);
#pragma unroll
    for (int j = 0; j < 4; ++j)
      bfv[j] = *(const bf16x8*)(&Bs[(wc0 + j * 16 + ln) * LDT + quad * 8]);
#pragma unroll
    for (int i = 0; i < 4; ++i)
#pragma unroll
      for (int j = 0; j < 4; ++j)
        acc[i][j] = __builtin_amdgcn_mfma_f32_16x16x32_bf16(af[i], bfv[j], acc[i][j], 0, 0, 0);
    __syncthreads();
#pragma unroll
    for (int p = 0; p < 2; ++p) { pa[p] = na[p]; pb[p] = nb[p]; }
  }

#pragma unroll
  for (int i = 0; i < 4; ++i) {
#pragma unroll
    for (int r = 0; r < 4; ++r) {
      int row = bm + wr0 + i * 16 + quad * 4 + r;
      if (row >= M) continue;
#pragma unroll
      for (int j = 0; j < 4; ++j) {
        int col = bn + wc0 + j * 16 + ln;
        Cout[(size_t)row * N + col] = f2b_rne(acc[i][j][r]);
      }
    }
  }

  float asv[4], adv[4];
#pragma unroll
  for (int j = 0; j < 4; ++j) {
    int col = bn + wc0 + j * 16 + ln;
    asv[j] = a_src[col];
    adv[j] = a_dst[col];
  }
  if (EMODE == 64) {
    const int head = (bn + wc0) >> 6;
#pragma unroll
    for (int i = 0; i < 4; ++i) {
#pragma unroll
      for (int r = 0; r < 4; ++r) {
        float ps = 0.f, pd = 0.f;
#pragma unroll
        for (int j = 0; j < 4; ++j) {
          ps = fmaf(acc[i][j][r], asv[j], ps);
          pd = fmaf(acc[i][j][r], adv[j], pd);
        }
        for (int off = 8; off; off >>= 1) {
          ps += __shfl_down(ps, off, 16);
          pd += __shfl_down(pd, off, 16);
        }
        if (ln == 0) {
          int row = bm + wr0 + i * 16 + quad * 4 + r;
          if (row < M) {
            es[(size_t)row * nh + head] = ps;
            ed[(size_t)row * nh + head] = pd;
          }
        }
      }
    }
  } else {
    float* esp = (float*)As;
    float* edp = esp + 256;
#pragma unroll
    for (int i = 0; i < 4; ++i) {
#pragma unroll
      for (int r = 0; r < 4; ++r) {
        float ps = 0.f, pd = 0.f;
#pragma unroll
        for (int j = 0; j < 4; ++j) {
          ps = fmaf(acc[i][j][r], asv[j], ps);
          pd = fmaf(acc[i][j][r], adv[j], pd);
        }
        for (int off = 8; off; off >>= 1) {
          ps += __shfl_down(ps, off, 16);
          pd += __shfl_down(pd, off, 16);
        }
        if (ln == 0) {
          int rl = wr0 + i * 16 + quad * 4 + r;
          esp[rl * 2 + (wc0 >> 6)] = ps;
          edp[rl * 2 + (wc0 >> 6)] = pd;
        }
      }
    }
    __syncthreads();
    if (tid < 128) {
      int row = bm + tid;
      if (row < M) {
        int head = bn >> 7;
        es[(size_t)row * nh + head] = esp[tid * 2] + esp[tid * 2 + 1];
        ed[(size_t)row * nh + head] = edp[tid * 2] + edp[tid * 2 + 1];
      }
    }
  }
}

// ---------------- skinny MFMA GEMM, N=64, split-K, fp32 partials ----------------
__global__ __launch_bounds__(256) void gemm_mfma_n64(
    const unsigned short* __restrict__ A, int lda,
    const unsigned short* __restrict__ BT, int ldb,
    float* __restrict__ Cp, int M, int kchunk)
{
  const int LDT = 72;
  __shared__ unsigned short As[128 * 72];
  __shared__ unsigned short Bs[64 * 72];
  const int tid  = threadIdx.x;
  const int wave = tid >> 6;
  const int lane = tid & 63;
  const int ln   = lane & 15;
  const int quad = lane >> 4;
  const int ks   = blockIdx.x;
  const int bm   = blockIdx.y * 128;
  const int k_beg = ks * kchunk;
  const int k_end = k_beg + kchunk;
  const int arow = tid >> 1;
  const int akb  = (tid & 1) * 32;
  const int brow = tid >> 2;
  const int bkb  = (tid & 3) * 16;

  f32x4 acc[2][4];
  const f32x4 z4 = {0.f, 0.f, 0.f, 0.f};
#pragma unroll
  for (int i = 0; i < 2; ++i)
#pragma unroll
    for (int j = 0; j < 4; ++j) acc[i][j] = z4;

  for (int k0 = k_beg; k0 < k_end; k0 += 64) {
    const unsigned short* ap = A + (size_t)(bm + arow) * lda + k0 + akb;
#pragma unroll
    for (int q = 0; q < 4; ++q)
      *(bf16x8*)(&As[arow * LDT + akb + q * 8]) = *(const bf16x8*)(ap + q * 8);
    const unsigned short* bp = BT + (size_t)brow * ldb + k0 + bkb;
#pragma unroll
    for (int q = 0; q < 2; ++q)
      *(bf16x8*)(&Bs[brow * LDT + bkb + q * 8]) = *(const bf16x8*)(bp + q * 8);
    __syncthreads();
#pragma unroll
    for (int kk = 0; kk < 2; ++kk) {
      bf16x8 af[2], bfv[4];
#pragma unroll
      for (int i = 0; i < 2; ++i)
        af[i] = *(const bf16x8*)(&As[(wave * 32 + i * 16 + ln) * LDT + kk * 32 + quad * 8]);
#pragma unroll
      for (int j = 0; j < 4; ++j)
        bfv[j] = *(const bf16x8*)(&Bs[(j * 16 + ln) * LDT + kk * 32 + quad * 8]);
#pragma unroll
      for (int i = 0; i < 2; ++i)
#pragma unroll
        for (int j = 0; j < 4; ++j)
          acc[i][j] = __builtin_amdgcn_mfma_f32_16x16x32_bf16(af[i], bfv[j], acc[i][j], 0, 0, 0);
    }
    __syncthreads();
  }
#pragma unroll
  for (int i = 0; i < 2; ++i)
#pragma unroll
    for (int r = 0; r < 4; ++r) {
      int row = bm + wave * 32 + i * 16 + quad * 4 + r;
#pragma unroll
      for (int j = 0; j < 4; ++j)
        Cp[((size_t)ks * M + row) * 64 + j * 16 + ln] = acc[i][j][r];
    }
}

// ---------------- fp partial reduce + bias -> bf16 into z cols [512,576) ----------------
__global__ void fp_finish(const float* __restrict__ Cp, int ksplit, int M,
                          const float* __restrict__ bfp,
                          unsigned short* __restrict__ zb)
{
  const int g = blockIdx.x;
  const int j = threadIdx.x;
  float s = bfp[j];
  for (int ks = 0; ks < ksplit; ++ks) s += Cp[((size_t)ks * M + g) * 64 + j];
  zb[(size_t)g * 576 + 512 + j] = f2b_rne(s);
}

// ---------------- mlp partial reduce + bias + relu + fc2 dot -> out ----------------
__global__ void mlp_finish(const float* __restrict__ Cp, int ksplit, int M,
                           const float* __restrict__ bfc1,
                           const float* __restrict__ Wfc2, const float* __restrict__ bfc2,
                           float* __restrict__ out)
{
  const int g = blockIdx.x;
  const int j = threadIdx.x;
  float s = bfc1[j];
  for (int ks = 0; ks < ksplit; ++ks) s += Cp[((size_t)ks * M + g) * 64 + j];
  s = s > 0.f ? s : 0.f;
  float term = s * Wfc2[j];
  for (int off = 32; off; off >>= 1) term += __shfl_down(term, off, 64);
  if (j == 0) out[g] = term + bfc2[0];
}

// ---------------- fused count: edge degrees + graph counts ----------------
__global__ void count_all(const int* __restrict__ ei, int E, int* __restrict__ deg,
                          const int* __restrict__ batch, int NN, int* __restrict__ gcnt,
                          int BE)
{
  int b = blockIdx.x;
  int t = threadIdx.x;
  if (b < BE) {
    int e = b * 256 + t;
    if (e < E) atomicAdd(&deg[ei[E + e]], 1);
  } else {
    int i = (b - BE) * 256 + t;
    if (i < NN) atomicAdd(&gcnt[batch[i]], 1);
  }
}

__global__ void fill_csr(const int* __restrict__ ei, int E, int* __restrict__ cursor,
                         const int* __restrict__ rowptr, int* __restrict__ csr_src)
{
  int e = blockIdx.x * 256 + threadIdx.x;
  if (e < E) {
    int d = ei[E + e];
    int pos = atomicAdd(&cursor[d], 1);
    csr_src[rowptr[d] + pos] = ei[e];
  }
}

// ---------------- fused 3-phase exclusive scans (node-deg scan + graph-count scan) ----
__device__ void scan_p1_body(const int* __restrict__ vals, int n, int* __restrict__ bsum,
                             int bb)
{
  __shared__ int red[256];
  int base = bb * 1024;
  int t = threadIdx.x;
  int s = 0;
#pragma unroll
  for (int i = 0; i < 4; ++i) {
    int idx = base + i * 256 + t;
    if (idx < n) s += vals[idx];
  }
  red[t] = s;
  __syncthreads();
  for (int off = 128; off; off >>= 1) {
    if (t < off) red[t] += red[t + off];
    __syncthreads();
  }
  if (t == 0) bsum[bb] = red[0];
}

__global__ void scan2_p1(const int* __restrict__ vA, int nA, int* __restrict__ bsA, int nbA,
                         const int* __restrict__ vB, int nB, int* __restrict__ bsB)
{
  int b = blockIdx.x;
  if (b < nbA) scan_p1_body(vA, nA, bsA, b);
  else         scan_p1_body(vB, nB, bsB, b - nbA);
}

__device__ void scan_p2_body(const int* __restrict__ bsum, int* __restrict__ bpre,
                             int nb, int* __restrict__ rowptr, int n)
{
  __shared__ int tmp[128];
  int t = threadIdx.x;
  int v = (t < nb) ? bsum[t] : 0;
  tmp[t] = v;
  __syncthreads();
  for (int off = 1; off < 128; off <<= 1) {
    int add = (t >= off) ? tmp[t - off] : 0;
    __syncthreads();
    tmp[t] += add;
    __syncthreads();
  }
  if (t < nb) bpre[t] = tmp[t] - v;
  if (t == 127) rowptr[n] = tmp[127];
}

__global__ void scan2_p2(const int* __restrict__ bsA, int* __restrict__ bpA, int nbA,
                         int* __restrict__ rpA, int nA,
                         const int* __restrict__ bsB, int* __restrict__ bpB, int nbB,
                         int* __restrict__ rpB, int nB)
{
  if (blockIdx.x == 0) scan_p2_body(bsA, bpA, nbA, rpA, nA);
  else                 scan_p2_body(bsB, bpB, nbB, rpB, nB);
}

__device__ void scan_p3_body(const int* __restrict__ vals, const int* __restrict__ bpre,
                             int n, int* __restrict__ rowptr, int bb)
{
  __shared__ int tmp[256];
  int t = threadIdx.x;
  int base = bb * 1024 + t * 4;
  int v[4]; int s = 0;
#pragma unroll
  for (int i = 0; i < 4; ++i) {
    int idx = base + i;
    v[i] = (idx < n) ? vals[idx] : 0;
    s += v[i];
  }
  tmp[t] = s;
  __syncthreads();
  for (int off = 1; off < 256; off <<= 1) {
    int add = (t >= off) ? tmp[t - off] : 0;
    __syncthreads();
    tmp[t] += add;
    __syncthreads();
  }
  int run = bpre[bb] + tmp[t] - s;
#pragma unroll
  for (int i = 0; i < 4; ++i) {
    int idx = base + i;
    if (idx < n) rowptr[idx] = run;
    run += v[i];
  }
}

__global__ void scan2_p3(const int* __restrict__ vA, const int* __restrict__ bpA, int nA,
                         int* __restrict__ rpA, int nbA,
                         const int* __restrict__ vB, const int* __restrict__ bpB, int nB,
                         int* __restrict__ rpB)
{
  int b = blockIdx.x;
  if (b < nbA) scan_p3_body(vA, bpA, nA, rpA, b);
  else         scan_p3_body(vB, bpB, nB, rpB, b - nbA);
}

// ---------------- attention weights, ONE pass: unnormalized w + dinv ----------------
__global__ void alpha_kernel(const float* __restrict__ es, const float* __restrict__ ed,
                             const int* __restrict__ rowptr, const int* __restrict__ csr_src,
                             float* __restrict__ w_csr, float* __restrict__ wself,
                             float* __restrict__ dinv, int N, int nh)
{
  int idx = blockIdx.x * 256 + threadIdx.x;
  if (idx >= N * nh) return;
  const int dst = idx / nh;
  const int h = idx - dst * nh;
  const float edh = ed[(size_t)dst * nh + h];
  const int beg = rowptr[dst], end = rowptr[dst + 1];
  float sum = 0.f;
  for (int e = beg; e < end; ++e) {
    int s = csr_src[e];
    float l = es[(size_t)s * nh + h] + edh;
    l = l >= 0.f ? l : NEG_SLOPE * l;
    float w = expf(l);
    w_csr[(size_t)e * nh + h] = w;
    sum += w;
  }
  float ls = es[(size_t)dst * nh + h] + edh;
  ls = ls >= 0.f ? ls : NEG_SLOPE * ls;
  float wsl = expf(ls);
  sum += wsl;
  wself[(size_t)dst * nh + h] = wsl;
  dinv[(size_t)dst * nh + h] = 1.0f / sum;
}

// ---------------- conv1 aggregate (unsliced): gather + dinv + bias + ELU -> bf16 ----------------
__global__ __launch_bounds__(256) void aggregate_b(
    const unsigned short* __restrict__ h,
    const float* __restrict__ w_csr, const float* __restrict__ wself,
    const float* __restrict__ dinv,
    const int* __restrict__ rowptr, const int* __restrict__ csr_src,
    const float* __restrict__ bias, unsigned short* __restrict__ out,
    int N, int nh, int C)
{
  const int HC = nh * C;
  const int CH8 = HC >> 3;
  const int dpb = 256 / CH8;
  const int grp = threadIdx.x / CH8;
  const int lane = threadIdx.x - grp * CH8;
  const int dst = blockIdx.x * dpb + grp;
  if (dst >= N) return;
  const int ch = lane << 3;
  const int head = ch / C;
  const int beg = rowptr[dst], end = rowptr[dst + 1];
  float acc[8] = {0.f, 0.f, 0.f, 0.f, 0.f, 0.f, 0.f, 0.f};
  int e = beg;
  for (; e + 1 < end; e += 2) {
    int s0 = csr_src[e], s1 = csr_src[e + 1];
    float a0 = w_csr[(size_t)e * nh + head];
    float a1 = w_csr[(size_t)(e + 1) * nh + head];
    bf16x8 h0 = *(const bf16x8*)(h + (size_t)s0 * HC + ch);
    bf16x8 h1 = *(const bf16x8*)(h + (size_t)s1 * HC + ch);
#pragma unroll
    for (int r = 0; r < 8; ++r) acc[r] = fmaf(a0, b2f(h0[r]), acc[r]);
#pragma unroll
    for (int r = 0; r < 8; ++r) acc[r] = fmaf(a1, b2f(h1[r]), acc[r]);
  }
  if (e < end) {
    int s0 = csr_src[e];
    float a0 = w_csr[(size_t)e * nh + head];
    bf16x8 h0 = *(const bf16x8*)(h + (size_t)s0 * HC + ch);
#pragma unroll
    for (int r = 0; r < 8; ++r) acc[r] = fmaf(a0, b2f(h0[r]), acc[r]);
  }
  {
    float a = wself[(size_t)dst * nh + head];
    bf16x8 hv = *(const bf16x8*)(h + (size_t)dst * HC + ch);
#pragma unroll
    for (int r = 0; r < 8; ++r) acc[r] = fmaf(a, b2f(hv[r]), acc[r]);
  }
  const float di = dinv[(size_t)dst * nh + head];
  bf16x8 o;
#pragma unroll
  for (int r = 0; r < 8; ++r) {
    float v = acc[r] * di + bias[ch + r];
    v = v > 0.f ? v : (expf(v) - 1.0f);
    o[r] = (short)f2b_rne(v);
  }
  *(bf16x8*)(out + (size_t)dst * HC + ch) = o;
}

// ---------------- conv2 aggregate + ELU + mean-pool (unsliced), one block/graph ----------------
__global__ __launch_bounds__(256) void agg_pool(
    const unsigned short* __restrict__ h,
    const float* __restrict__ w_csr, const float* __restrict__ wself,
    const float* __restrict__ dinv,
    const int* __restrict__ rowptr, const int* __restrict__ csr_src,
    const float* __restrict__ bias, const int* __restrict__ grp,
    unsigned short* __restrict__ zb)
{
  const int g = blockIdx.x;
  const int wave = threadIdx.x >> 6;
  const int lane = threadIdx.x & 63;
  const int ch = lane << 3;
  const int head = lane >> 4;          // ch/128
  const int gbeg = grp[g], gend = grp[g + 1];
  float bch[8];
#pragma unroll
  for (int r = 0; r < 8; ++r) bch[r] = bias[ch + r];
  float pool[8] = {0.f, 0.f, 0.f, 0.f, 0.f, 0.f, 0.f, 0.f};

  for (int node = gbeg + wave; node < gend; node += 4) {
    const int beg = rowptr[node], end = rowptr[node + 1];
    float acc[8] = {0.f, 0.f, 0.f, 0.f, 0.f, 0.f, 0.f, 0.f};
    int e = beg;
    for (; e + 1 < end; e += 2) {
      int s0 = csr_src[e], s1 = csr_src[e + 1];
      float a0 = w_csr[(size_t)e * 4 + head];
      float a1 = w_csr[(size_t)(e + 1) * 4 + head];
      bf16x8 h0 = *(const bf16x8*)(h + (size_t)s0 * 512 + ch);
      bf16x8 h1 = *(const bf16x8*)(h + (size_t)s1 * 512 + ch);
#pragma unroll
      for (int r = 0; r < 8; ++r) acc[r] = fmaf(a0, b2f(h0[r]), acc[r]);
#pragma unroll
      for (int r = 0; r < 8; ++r) acc[r] = fmaf(a1, b2f(h1[r]), acc[r]);
    }
    if (e < end) {
      int s0 = csr_src[e];
      float a0 = w_csr[(size_t)e * 4 + head];
      bf16x8 h0 = *(const bf16x8*)(h + (size_t)s0 * 512 + ch);
#pragma unroll
      for (int r = 0; r < 8; ++r) acc[r] = fmaf(a0, b2f(h0[r]), acc[r]);
    }
    {
      float a = wself[(size_t)node * 4 + head];
      bf16x8 hv = *(const bf16x8*)(h + (size_t)node * 512 + ch);
#pragma unroll
      for (int r = 0; r < 8; ++r) acc[r] = fmaf(a, b2f(hv[r]), acc[r]);
    }
    const float di = dinv[(size_t)node * 4 + head];
#pragma unroll
    for (int r = 0; r < 8; ++r) {
      float v = acc[r] * di + bch[r];
      v = v > 0.f ? v : (expf(v) - 1.0f);   // ELU
      pool[r] += v;
    }
  }

  __shared__ float red[4][512];
#pragma unroll
  for (int r = 0; r < 8; ++r) red[wave][ch + r] = pool[r];
  __syncthreads();
  const float inv = 1.0f / (float)max(gend - gbeg, 1);
#pragma unroll
  for (int k = 0; k < 2; ++k) {
    int c = threadIdx.x + k * 256;
    float s = (red[0][c] + red[1][c]) + (red[2][c] + red[3][c]);
    zb[(size_t)g * 576 + c] = f2b_rne(s * inv);
  }
}

// ---------------- launcher ----------------
extern "C" void kernel_launch(void* const* d_in, const int* in_sizes, int n_in,
                              void* d_out, int out_size, void* d_ws, size_t ws_size,
                              hipStream_t stream)
{
  const float* x      = (const float*)d_in[0];
  const int*   ei     = (const int*)d_in[1];
  const int*   batch  = (const int*)d_in[2];
  const float* fp     = (const float*)d_in[3];
  const float* W1     = (const float*)d_in[4];
  const float* a_src1 = (const float*)d_in[5];
  const float* a_dst1 = (const float*)d_in[6];
  const float* b1     = (const float*)d_in[7];
  const float* W2     = (const float*)d_in[8];
  const float* a_src2 = (const float*)d_in[9];
  const float* a_dst2 = (const float*)d_in[10];
  const float* b2     = (const float*)d_in[11];
  const float* Wfp    = (const float*)d_in[12];
  const float* bfp    = (const float*)d_in[13];
  const float* Wfc1   = (const float*)d_in[14];
  const float* bfc1   = (const float*)d_in[15];
  const float* Wfc2   = (const float*)d_in[16];
  const float* bfc2   = (const float*)d_in[17];
  float* out = (float*)d_out;

  const int NN = in_sizes[0] / 128;
  const int E  = in_sizes[1] / 2;
  const int G  = in_sizes[3] / 2048;
  const int FIN = 128, H = 4, C1 = 64, C2 = 128;
  const int HC1 = H * C1;   // 256
  const int HC2 = H * C2;   // 512
  const int KFP = in_sizes[3] / G;   // 2048
  const int KZ  = HC2 + 64;          // 576
  const int KS_FP = 16;
  const int KS_Z  = 9;

  // ---- workspace: liverange-overlaid regions ----
  char* base = (char*)d_ws;
  size_t off = 0;
  auto alloc = [&](size_t bytes) {
    char* p = base + off; off += (bytes + 255) & ~(size_t)255; return p;
  };
  // Region A: early xb+h1b; late h2b
  size_t xb_sz  = ((size_t)NN * FIN * 2 + 255) & ~(size_t)255;
  size_t h1b_sz = (size_t)NN * HC1 * 2;
  size_t h2b_sz = (size_t)NN * HC2 * 2;
  size_t rA = xb_sz + h1b_sz; if (h2b_sz > rA) rA = h2b_sz;
  char* RA = alloc(rA);
  unsigned short* xb  = (unsigned short*)RA;
  unsigned short* h1b = (unsigned short*)(RA + xb_sz);
  unsigned short* h2b = (unsigned short*)RA;
  // Region B: early fpb+Cp_fp; late agg1b
  size_t fpb_sz  = ((size_t)G * KFP * 2 + 255) & ~(size_t)255;
  size_t cpfp_sz = (size_t)KS_FP * G * 64 * 4;
  size_t agg1_sz = (size_t)NN * HC1 * 2;
  size_t rB = fpb_sz + cpfp_sz; if (agg1_sz > rB) rB = agg1_sz;
  char* RB = alloc(rB);
  unsigned short* fpb   = (unsigned short*)RB;
  float*          Cp_fp = (float*)(RB + fpb_sz);
  unsigned short* agg1b = (unsigned short*)RB;
  // Region C: attn buffers (conv1 then conv2 sequentially)
  float* w1     = (float*)alloc((size_t)E * H * 4);
  float* wself1 = (float*)alloc((size_t)NN * H * 4);
  float* es1    = (float*)alloc((size_t)NN * H * 4);
  float* ed1    = (float*)alloc((size_t)NN * H * 4);
  float* dinv1  = (float*)alloc((size_t)NN * H * 4);
  float* w2 = w1, *wself2 = wself1, *es2 = es1, *ed2 = ed1, *dinv2 = dinv1;
  // Persistent small buffers
  unsigned short* zb    = (unsigned short*)alloc((size_t)G * KZ * 2);
  float*          Cp_z  = (float*)alloc((size_t)KS_Z * G * 64 * 4);
  unsigned short* W1T   = (unsigned short*)alloc((size_t)HC1 * FIN * 2);
  unsigned short* W2T   = (unsigned short*)alloc((size_t)HC2 * HC1 * 2);
  unsigned short* WfpT  = (unsigned short*)alloc((size_t)64 * KFP * 2);
  unsigned short* Wfc1T = (unsigned short*)alloc((size_t)64 * KZ * 2);
  // int arena: deg/cursor/gcnt contiguous (single memset covers exactly this span)
  int* iarena   = (int*)alloc(((size_t)2 * NN + G) * 4);
  int* deg      = iarena;
  int* cursor   = iarena + NN;
  int* gcnt     = iarena + 2 * NN;
  int* rowptr_n = (int*)alloc(((size_t)NN + 1) * 4);
  int* rowptr_g = (int*)alloc(((size_t)G + 1) * 4);
  int* csr_src  = (int*)alloc((size_t)E * 4);
  int* bsumA    = (int*)alloc(128 * 4);
  int* bpreA    = (int*)alloc(128 * 4);
  int* bsumB    = (int*)alloc(128 * 4);
  int* bpreB    = (int*)alloc(128 * 4);

  // ---- fused prep (cvt x, cvt fp, 4 transposes) ----
  const size_t nx = (size_t)NN * FIN;
  const size_t nf = (size_t)G * KFP;
  const int B0 = (int)((nx + 255) / 256);
  const int B1 = (int)((nf + 255) / 256);
  {
    int nb = B0 + B1 + 128 + 512 + 512 + 144;
    prep_all<<<nb, 256, 0, stream>>>(x, xb, nx, B0, fp, fpb, nf, B1,
                                     W1, W1T, W2, W2T, Wfp, WfpT, Wfc1, Wfc1T);
  }

  // ---- fingerprint branch (finishes before agg1b is written — same stream) ----
  {
    dim3 gg(KS_FP, G / 128);
    gemm_mfma_n64<<<gg, 256, 0, stream>>>(fpb, KFP, WfpT, KFP, Cp_fp, G, KFP / KS_FP);
    fp_finish<<<G, 64, 0, stream>>>(Cp_fp, KS_FP, G, bfp, zb);
  }

  // ---- CSR by dst + graph segment ptrs (fused counts + fused scans) ----
  hipMemsetAsync(iarena, 0, sizeof(int) * ((size_t)2 * NN + G), stream);
  {
    int BE = (E + 255) / 256;
    int BN = (NN + 255) / 256;
    count_all<<<BE + BN, 256, 0, stream>>>(ei, E, deg, batch, NN, gcnt, BE);
  }
  {
    int nbA = (NN + 1023) / 1024;   // deg scan blocks
    int nbB = (G + 1023) / 1024;    // gcnt scan blocks
    scan2_p1<<<nbA + nbB, 256, 0, stream>>>(deg, NN, bsumA, nbA, gcnt, G, bsumB);
    scan2_p2<<<2, 128, 0, stream>>>(bsumA, bpreA, nbA, rowptr_n, NN,
                                    bsumB, bpreB, nbB, rowptr_g, G);
    scan2_p3<<<nbA + nbB, 256, 0, stream>>>(deg, bpreA, NN, rowptr_n, nbA,
                                            gcnt, bpreB, G, rowptr_g);
  }
  fill_csr<<<(E + 255) / 256, 256, 0, stream>>>(ei, E, cursor, rowptr_n, csr_src);

  // ---- conv1: GEMM (+fused e) -> alpha -> aggregate ----
  {
    dim3 gg(HC1 / 128, (NN + 127) / 128);
    gemm_mfma<64><<<gg, 256, 0, stream>>>(xb, W1T, h1b, NN, HC1, FIN,
                                          a_src1, a_dst1, es1, ed1, H);
  }
  alpha_kernel<<<(NN * H + 255) / 256, 256, 0, stream>>>(es1, ed1, rowptr_n, csr_src,
                                                         w1, wself1, dinv1, NN, H);
  aggregate_b<<<(NN + 7) / 8, 256, 0, stream>>>(h1b, w1, wself1, dinv1, rowptr_n, csr_src,
                                                b1, agg1b, NN, H, C1);

  // ---- conv2: GEMM (+fused e) -> alpha -> fused aggregate+pool ----
  {
    dim3 gg(HC2 / 128, (NN + 127) / 128);
    gemm_mfma<128><<<gg, 256, 0, stream>>>(agg1b, W2T, h2b, NN, HC2, HC1,
                                           a_src2, a_dst2, es2, ed2, H);
  }
  alpha_kernel<<<(NN * H + 255) / 256, 256, 0, stream>>>(es2, ed2, rowptr_n, csr_src,
                                                         w2, wself2, dinv2, NN, H);
  agg_pool<<<G, 256, 0, stream>>>(h2b, w2, wself2, dinv2, rowptr_n, csr_src,
                                  b2, rowptr_g, zb);

  // ---- head ----
  {
    dim3 gg(KS_Z, G / 128);
    gemm_mfma_n64<<<gg, 256, 0, stream>>>(zb, KZ, Wfc1T, KZ, Cp_z, G, KZ / KS_Z);
    mlp_finish<<<G, 64, 0, stream>>>(Cp_z, KS_Z, G, bfc1, Wfc2, bfc2, out);
  }
}

// Round 12
// 462.272 us; speedup vs baseline: 3.9791x; 1.0649x over previous
//
#include <hip/hip_runtime.h>
#include <math.h>

#define NEG_SLOPE 0.2f

typedef __attribute__((ext_vector_type(8))) short bf16x8;   // 8 bf16 (4 VGPRs)
typedef __attribute__((ext_vector_type(4))) float f32x4;    // MFMA acc
typedef __attribute__((ext_vector_type(2))) float f32x2;

__device__ __forceinline__ float b2f(short s) {
  return __uint_as_float(((unsigned int)(unsigned short)s) << 16);
}
__device__ __forceinline__ unsigned short f2b_rne(float f) {
  unsigned int u = __float_as_uint(f);
  u = (u + 0x7FFF + ((u >> 16) & 1)) >> 16;
  return (unsigned short)u;
}

// 8 fp8(e4m3) bytes -> 8 floats (HW cvt)
__device__ __forceinline__ void fp8x8_to_f32(uint2 raw, float* f) {
  f32x2 a = __builtin_amdgcn_cvt_pk_f32_fp8((int)raw.x, false);
  f32x2 b = __builtin_amdgcn_cvt_pk_f32_fp8((int)raw.x, true);
  f32x2 c = __builtin_amdgcn_cvt_pk_f32_fp8((int)raw.y, false);
  f32x2 d = __builtin_amdgcn_cvt_pk_f32_fp8((int)raw.y, true);
  f[0] = a[0]; f[1] = a[1]; f[2] = b[0]; f[3] = b[1];
  f[4] = c[0]; f[5] = c[1]; f[6] = d[0]; f[7] = d[1];
}

// ---------------- fused prep: cvt x, cvt fp, 4 weight transposes ----------------
__device__ __forceinline__ void tr_one(const float* __restrict__ W,
                                       unsigned short* __restrict__ WT,
                                       int K, int N, int idx)
{
  if (idx < K * N) {
    int k = idx / N, n = idx - k * N;
    WT[(size_t)n * K + k] = f2b_rne(W[idx]);
  }
}

__global__ __launch_bounds__(256) void prep_all(
    const float* __restrict__ x, unsigned short* __restrict__ xb, size_t nx, int B0,
    const float* __restrict__ fp, unsigned short* __restrict__ fpb, size_t nf, int B1,
    const float* __restrict__ W1, unsigned short* __restrict__ W1T,
    const float* __restrict__ W2, unsigned short* __restrict__ W2T,
    const float* __restrict__ Wfp, unsigned short* __restrict__ WfpT,
    const float* __restrict__ Wfc1, unsigned short* __restrict__ Wfc1T)
{
  int b = blockIdx.x;
  const int t = threadIdx.x;
  if (b < B0) {
    size_t i = (size_t)b * 256 + t;
    if (i < nx) xb[i] = f2b_rne(x[i]);
    return;
  }
  b -= B0;
  if (b < B1) {
    size_t i = (size_t)b * 256 + t;
    if (i < nf) fpb[i] = f2b_rne(fp[i]);
    return;
  }
  b -= B1;
  if (b < 128) { tr_one(W1, W1T, 128, 256, b * 256 + t); return; }
  b -= 128;
  if (b < 512) { tr_one(W2, W2T, 256, 512, b * 256 + t); return; }
  b -= 512;
  if (b < 512) { tr_one(Wfp, WfpT, 2048, 64, b * 256 + t); return; }
  b -= 512;
  tr_one(Wfc1, Wfc1T, 576, 64, b * 256 + t);
}

// ---------------- MFMA GEMM + fused e epilogue; C in fp8(e4m3) ----------------
// A bf16 [M,K], BT bf16 [N,K]. BM=BN=128, BK=32, 4 waves, reg-prefetch dbuf.
// EMODE = channels-per-head (64 or 128). es/ed from fp32 acc (full precision).
template<int EMODE>
__global__ __launch_bounds__(256) void gemm_mfma(
    const unsigned short* __restrict__ A, const unsigned short* __restrict__ BT,
    unsigned char* __restrict__ Cout, int M, int N, int K,
    const float* __restrict__ a_src, const float* __restrict__ a_dst,
    float* __restrict__ es, float* __restrict__ ed, int nh)
{
  const int LDT = 40;
  __shared__ unsigned short As[128 * 40];
  __shared__ unsigned short Bs[128 * 40];
  const int tid  = threadIdx.x;
  const int wave = tid >> 6;
  const int lane = tid & 63;
  const int ln   = lane & 15;
  const int quad = lane >> 4;
  const int wr0  = (wave >> 1) * 64;
  const int wc0  = (wave & 1) * 64;
  const int bm   = blockIdx.y * 128;
  const int bn   = blockIdx.x * 128;
  const int srow  = tid >> 2;
  const int skoff = (tid & 3) * 8;

  f32x4 acc[4][4];
  const f32x4 z4 = {0.f, 0.f, 0.f, 0.f};
#pragma unroll
  for (int i = 0; i < 4; ++i)
#pragma unroll
    for (int j = 0; j < 4; ++j) acc[i][j] = z4;

  const bf16x8 zb8 = {0, 0, 0, 0, 0, 0, 0, 0};
  bf16x8 pa[2] = {zb8, zb8}, pb[2] = {zb8, zb8};
  bf16x8 na[2] = {zb8, zb8}, nb[2] = {zb8, zb8};
#pragma unroll
  for (int p = 0; p < 2; ++p) {
    int r = srow + p * 64;
    pa[p] = (bm + r < M) ? *(const bf16x8*)(A + (size_t)(bm + r) * K + skoff) : zb8;
    pb[p] = *(const bf16x8*)(BT + (size_t)(bn + r) * K + skoff);
  }

  for (int k0 = 0; k0 < K; k0 += 32) {
#pragma unroll
    for (int p = 0; p < 2; ++p) {
      int r = srow + p * 64;
      *(bf16x8*)(&As[r * LDT + skoff]) = pa[p];
      *(bf16x8*)(&Bs[r * LDT + skoff]) = pb[p];
    }
    __syncthreads();
    if (k0 + 32 < K) {
      int kn = k0 + 32;
#pragma unroll
      for (int p = 0; p < 2; ++p) {
        int r = srow + p * 64;
        na[p] = (bm + r < M) ? *(const bf16x8*)(A + (size_t)(bm + r) * K + kn + skoff) : zb8;
        nb[p] = *(const bf16x8*)(BT + (size_t)(bn + r) * K + kn + skoff);
      }
    }
    bf16x8 af[4], bfv[4];
#pragma unroll
    for (int i = 0; i < 4; ++i)
      af[i] = *(const bf16x8*)(&As[(wr0 + i * 16 + ln) * LDT + quad * 8]);
#pragma unroll
    for (int j = 0; j < 4; ++j)
      bfv[j] = *(const bf16x8*)(&Bs[(wc0 + j * 16 + ln) * LDT + quad * 8]);
#pragma unroll
    for (int i = 0; i < 4; ++i)
#pragma unroll
      for (int j = 0; j < 4; ++j)
        acc[i][j] = __builtin_amdgcn_mfma_f32_16x16x32_bf16(af[i], bfv[j], acc[i][j], 0, 0, 0);
    __syncthreads();
#pragma unroll
    for (int p = 0; p < 2; ++p) { pa[p] = na[p]; pb[p] = nb[p]; }
  }

  // ---- C store (fp8 e4m3) ----
#pragma unroll
  for (int i = 0; i < 4; ++i) {
#pragma unroll
    for (int r = 0; r < 4; ++r) {
      int row = bm + wr0 + i * 16 + quad * 4 + r;
      if (row >= M) continue;
      int p01 = __builtin_amdgcn_cvt_pk_fp8_f32(acc[i][0][r], acc[i][1][r], 0, false);
      int p23 = __builtin_amdgcn_cvt_pk_fp8_f32(acc[i][2][r], acc[i][3][r], 0, false);
      size_t rb = (size_t)row * N + bn + wc0 + ln;
      Cout[rb +  0] = (unsigned char)(p01 & 0xff);
      Cout[rb + 16] = (unsigned char)((p01 >> 8) & 0xff);
      Cout[rb + 32] = (unsigned char)(p23 & 0xff);
      Cout[rb + 48] = (unsigned char)((p23 >> 8) & 0xff);
    }
  }

  // ---- fused e_src/e_dst (from fp32 acc) ----
  float asv[4], adv[4];
#pragma unroll
  for (int j = 0; j < 4; ++j) {
    int col = bn + wc0 + j * 16 + ln;
    asv[j] = a_src[col];
    adv[j] = a_dst[col];
  }
  if (EMODE == 64) {
    const int head = (bn + wc0) >> 6;
#pragma unroll
    for (int i = 0; i < 4; ++i) {
#pragma unroll
      for (int r = 0; r < 4; ++r) {
        float ps = 0.f, pd = 0.f;
#pragma unroll
        for (int j = 0; j < 4; ++j) {
          ps = fmaf(acc[i][j][r], asv[j], ps);
          pd = fmaf(acc[i][j][r], adv[j], pd);
        }
        for (int off = 8; off; off >>= 1) {
          ps += __shfl_down(ps, off, 16);
          pd += __shfl_down(pd, off, 16);
        }
        if (ln == 0) {
          int row = bm + wr0 + i * 16 + quad * 4 + r;
          if (row < M) {
            es[(size_t)row * nh + head] = ps;
            ed[(size_t)row * nh + head] = pd;
          }
        }
      }
    }
  } else {
    float* esp = (float*)As;
    float* edp = esp + 256;
#pragma unroll
    for (int i = 0; i < 4; ++i) {
#pragma unroll
      for (int r = 0; r < 4; ++r) {
        float ps = 0.f, pd = 0.f;
#pragma unroll
        for (int j = 0; j < 4; ++j) {
          ps = fmaf(acc[i][j][r], asv[j], ps);
          pd = fmaf(acc[i][j][r], adv[j], pd);
        }
        for (int off = 8; off; off >>= 1) {
          ps += __shfl_down(ps, off, 16);
          pd += __shfl_down(pd, off, 16);
        }
        if (ln == 0) {
          int rl = wr0 + i * 16 + quad * 4 + r;
          esp[rl * 2 + (wc0 >> 6)] = ps;
          edp[rl * 2 + (wc0 >> 6)] = pd;
        }
      }
    }
    __syncthreads();
    if (tid < 128) {
      int row = bm + tid;
      if (row < M) {
        int head = bn >> 7;
        es[(size_t)row * nh + head] = esp[tid * 2] + esp[tid * 2 + 1];
        ed[(size_t)row * nh + head] = edp[tid * 2] + edp[tid * 2 + 1];
      }
    }
  }
}

// ---------------- skinny MFMA GEMM, N=64, split-K, fp32 partials ----------------
__global__ __launch_bounds__(256) void gemm_mfma_n64(
    const unsigned short* __restrict__ A, int lda,
    const unsigned short* __restrict__ BT, int ldb,
    float* __restrict__ Cp, int M, int kchunk)
{
  const int LDT = 72;
  __shared__ unsigned short As[128 * 72];
  __shared__ unsigned short Bs[64 * 72];
  const int tid  = threadIdx.x;
  const int wave = tid >> 6;
  const int lane = tid & 63;
  const int ln   = lane & 15;
  const int quad = lane >> 4;
  const int ks   = blockIdx.x;
  const int bm   = blockIdx.y * 128;
  const int k_beg = ks * kchunk;
  const int k_end = k_beg + kchunk;
  const int arow = tid >> 1;
  const int akb  = (tid & 1) * 32;
  const int brow = tid >> 2;
  const int bkb  = (tid & 3) * 16;

  f32x4 acc[2][4];
  const f32x4 z4 = {0.f, 0.f, 0.f, 0.f};
#pragma unroll
  for (int i = 0; i < 2; ++i)
#pragma unroll
    for (int j = 0; j < 4; ++j) acc[i][j] = z4;

  for (int k0 = k_beg; k0 < k_end; k0 += 64) {
    const unsigned short* ap = A + (size_t)(bm + arow) * lda + k0 + akb;
#pragma unroll
    for (int q = 0; q < 4; ++q)
      *(bf16x8*)(&As[arow * LDT + akb + q * 8]) = *(const bf16x8*)(ap + q * 8);
    const unsigned short* bp = BT + (size_t)brow * ldb + k0 + bkb;
#pragma unroll
    for (int q = 0; q < 2; ++q)
      *(bf16x8*)(&Bs[brow * LDT + bkb + q * 8]) = *(const bf16x8*)(bp + q * 8);
    __syncthreads();
#pragma unroll
    for (int kk = 0; kk < 2; ++kk) {
      bf16x8 af[2], bfv[4];
#pragma unroll
      for (int i = 0; i < 2; ++i)
        af[i] = *(const bf16x8*)(&As[(wave * 32 + i * 16 + ln) * LDT + kk * 32 + quad * 8]);
#pragma unroll
      for (int j = 0; j < 4; ++j)
        bfv[j] = *(const bf16x8*)(&Bs[(j * 16 + ln) * LDT + kk * 32 + quad * 8]);
#pragma unroll
      for (int i = 0; i < 2; ++i)
#pragma unroll
        for (int j = 0; j < 4; ++j)
          acc[i][j] = __builtin_amdgcn_mfma_f32_16x16x32_bf16(af[i], bfv[j], acc[i][j], 0, 0, 0);
    }
    __syncthreads();
  }
#pragma unroll
  for (int i = 0; i < 2; ++i)
#pragma unroll
    for (int r = 0; r < 4; ++r) {
      int row = bm + wave * 32 + i * 16 + quad * 4 + r;
#pragma unroll
      for (int j = 0; j < 4; ++j)
        Cp[((size_t)ks * M + row) * 64 + j * 16 + ln] = acc[i][j][r];
    }
}

// ---------------- fp partial reduce + bias -> bf16 into z cols [512,576) ----------------
__global__ void fp_finish(const float* __restrict__ Cp, int ksplit, int M,
                          const float* __restrict__ bfp,
                          unsigned short* __restrict__ zb)
{
  const int g = blockIdx.x;
  const int j = threadIdx.x;
  float s = bfp[j];
  for (int ks = 0; ks < ksplit; ++ks) s += Cp[((size_t)ks * M + g) * 64 + j];
  zb[(size_t)g * 576 + 512 + j] = f2b_rne(s);
}

// ---------------- mlp partial reduce + bias + relu + fc2 dot -> out ----------------
__global__ void mlp_finish(const float* __restrict__ Cp, int ksplit, int M,
                           const float* __restrict__ bfc1,
                           const float* __restrict__ Wfc2, const float* __restrict__ bfc2,
                           float* __restrict__ out)
{
  const int g = blockIdx.x;
  const int j = threadIdx.x;
  float s = bfc1[j];
  for (int ks = 0; ks < ksplit; ++ks) s += Cp[((size_t)ks * M + g) * 64 + j];
  s = s > 0.f ? s : 0.f;
  float term = s * Wfc2[j];
  for (int off = 32; off; off >>= 1) term += __shfl_down(term, off, 64);
  if (j == 0) out[g] = term + bfc2[0];
}

// ---------------- fused count: edge degrees + graph counts ----------------
__global__ void count_all(const int* __restrict__ ei, int E, int* __restrict__ deg,
                          const int* __restrict__ batch, int NN, int* __restrict__ gcnt,
                          int BE)
{
  int b = blockIdx.x;
  int t = threadIdx.x;
  if (b < BE) {
    int e = b * 256 + t;
    if (e < E) atomicAdd(&deg[ei[E + e]], 1);
  } else {
    int i = (b - BE) * 256 + t;
    if (i < NN) atomicAdd(&gcnt[batch[i]], 1);
  }
}

__global__ void fill_csr(const int* __restrict__ ei, int E, int* __restrict__ cursor,
                         const int* __restrict__ rowptr, int* __restrict__ csr_src)
{
  int e = blockIdx.x * 256 + threadIdx.x;
  if (e < E) {
    int d = ei[E + e];
    int pos = atomicAdd(&cursor[d], 1);
    csr_src[rowptr[d] + pos] = ei[e];
  }
}

// ---------------- fused 3-phase exclusive scans ----------------
__device__ void scan_p1_body(const int* __restrict__ vals, int n, int* __restrict__ bsum,
                             int bb)
{
  __shared__ int red[256];
  int base = bb * 1024;
  int t = threadIdx.x;
  int s = 0;
#pragma unroll
  for (int i = 0; i < 4; ++i) {
    int idx = base + i * 256 + t;
    if (idx < n) s += vals[idx];
  }
  red[t] = s;
  __syncthreads();
  for (int off = 128; off; off >>= 1) {
    if (t < off) red[t] += red[t + off];
    __syncthreads();
  }
  if (t == 0) bsum[bb] = red[0];
}

__global__ void scan2_p1(const int* __restrict__ vA, int nA, int* __restrict__ bsA, int nbA,
                         const int* __restrict__ vB, int nB, int* __restrict__ bsB)
{
  int b = blockIdx.x;
  if (b < nbA) scan_p1_body(vA, nA, bsA, b);
  else         scan_p1_body(vB, nB, bsB, b - nbA);
}

__device__ void scan_p2_body(const int* __restrict__ bsum, int* __restrict__ bpre,
                             int nb, int* __restrict__ rowptr, int n)
{
  __shared__ int tmp[128];
  int t = threadIdx.x;
  int v = (t < nb) ? bsum[t] : 0;
  tmp[t] = v;
  __syncthreads();
  for (int off = 1; off < 128; off <<= 1) {
    int add = (t >= off) ? tmp[t - off] : 0;
    __syncthreads();
    tmp[t] += add;
    __syncthreads();
  }
  if (t < nb) bpre[t] = tmp[t] - v;
  if (t == 127) rowptr[n] = tmp[127];
}

__global__ void scan2_p2(const int* __restrict__ bsA, int* __restrict__ bpA, int nbA,
                         int* __restrict__ rpA, int nA,
                         const int* __restrict__ bsB, int* __restrict__ bpB, int nbB,
                         int* __restrict__ rpB, int nB)
{
  if (blockIdx.x == 0) scan_p2_body(bsA, bpA, nbA, rpA, nA);
  else                 scan_p2_body(bsB, bpB, nbB, rpB, nB);
}

__device__ void scan_p3_body(const int* __restrict__ vals, const int* __restrict__ bpre,
                             int n, int* __restrict__ rowptr, int bb)
{
  __shared__ int tmp[256];
  int t = threadIdx.x;
  int base = bb * 1024 + t * 4;
  int v[4]; int s = 0;
#pragma unroll
  for (int i = 0; i < 4; ++i) {
    int idx = base + i;
    v[i] = (idx < n) ? vals[idx] : 0;
    s += v[i];
  }
  tmp[t] = s;
  __syncthreads();
  for (int off = 1; off < 256; off <<= 1) {
    int add = (t >= off) ? tmp[t - off] : 0;
    __syncthreads();
    tmp[t] += add;
    __syncthreads();
  }
  int run = bpre[bb] + tmp[t] - s;
#pragma unroll
  for (int i = 0; i < 4; ++i) {
    int idx = base + i;
    if (idx < n) rowptr[idx] = run;
    run += v[i];
  }
}

__global__ void scan2_p3(const int* __restrict__ vA, const int* __restrict__ bpA, int nA,
                         int* __restrict__ rpA, int nbA,
                         const int* __restrict__ vB, const int* __restrict__ bpB, int nB,
                         int* __restrict__ rpB)
{
  int b = blockIdx.x;
  if (b < nbA) scan_p3_body(vA, bpA, nA, rpA, b);
  else         scan_p3_body(vB, bpB, nB, rpB, b - nbA);
}

// ---------------- attention weights, one pass: unnormalized w + dinv ----------------
__global__ void alpha_kernel(const float* __restrict__ es, const float* __restrict__ ed,
                             const int* __restrict__ rowptr, const int* __restrict__ csr_src,
                             float* __restrict__ w_csr, float* __restrict__ wself,
                             float* __restrict__ dinv, int N, int nh)
{
  int idx = blockIdx.x * 256 + threadIdx.x;
  if (idx >= N * nh) return;
  const int dst = idx / nh;
  const int h = idx - dst * nh;
  const float edh = ed[(size_t)dst * nh + h];
  const int beg = rowptr[dst], end = rowptr[dst + 1];
  float sum = 0.f;
  for (int e = beg; e < end; ++e) {
    int s = csr_src[e];
    float l = es[(size_t)s * nh + h] + edh;
    l = l >= 0.f ? l : NEG_SLOPE * l;
    float w = expf(l);
    w_csr[(size_t)e * nh + h] = w;
    sum += w;
  }
  float ls = es[(size_t)dst * nh + h] + edh;
  ls = ls >= 0.f ? ls : NEG_SLOPE * ls;
  float wsl = expf(ls);
  sum += wsl;
  wself[(size_t)dst * nh + h] = wsl;
  dinv[(size_t)dst * nh + h] = 1.0f / sum;
}

// ---------------- conv1 aggregate: fp8 gather + dinv + bias + ELU -> bf16 ----------------
__global__ __launch_bounds__(256) void aggregate_b(
    const unsigned char* __restrict__ h,
    const float* __restrict__ w_csr, const float* __restrict__ wself,
    const float* __restrict__ dinv,
    const int* __restrict__ rowptr, const int* __restrict__ csr_src,
    const float* __restrict__ bias, unsigned short* __restrict__ out,
    int N, int nh, int C)
{
  const int HC = nh * C;                 // 256
  const int CH8 = HC >> 3;               // 32 lanes/dst
  const int dpb = 256 / CH8;             // 8 dsts/block
  const int grp = threadIdx.x / CH8;
  const int lane = threadIdx.x - grp * CH8;
  const int dst = blockIdx.x * dpb + grp;
  if (dst >= N) return;
  const int ch = lane << 3;
  const int head = ch / C;
  const int beg = rowptr[dst], end = rowptr[dst + 1];
  float acc[8] = {0.f, 0.f, 0.f, 0.f, 0.f, 0.f, 0.f, 0.f};
  float hv[8];
  int e = beg;
  for (; e + 1 < end; e += 2) {
    int s0 = csr_src[e], s1 = csr_src[e + 1];
    float a0 = w_csr[(size_t)e * nh + head];
    float a1 = w_csr[(size_t)(e + 1) * nh + head];
    uint2 r0 = *(const uint2*)(h + (size_t)s0 * HC + ch);
    uint2 r1 = *(const uint2*)(h + (size_t)s1 * HC + ch);
    fp8x8_to_f32(r0, hv);
#pragma unroll
    for (int r = 0; r < 8; ++r) acc[r] = fmaf(a0, hv[r], acc[r]);
    fp8x8_to_f32(r1, hv);
#pragma unroll
    for (int r = 0; r < 8; ++r) acc[r] = fmaf(a1, hv[r], acc[r]);
  }
  if (e < end) {
    int s0 = csr_src[e];
    float a0 = w_csr[(size_t)e * nh + head];
    uint2 r0 = *(const uint2*)(h + (size_t)s0 * HC + ch);
    fp8x8_to_f32(r0, hv);
#pragma unroll
    for (int r = 0; r < 8; ++r) acc[r] = fmaf(a0, hv[r], acc[r]);
  }
  {
    float a = wself[(size_t)dst * nh + head];
    uint2 r0 = *(const uint2*)(h + (size_t)dst * HC + ch);
    fp8x8_to_f32(r0, hv);
#pragma unroll
    for (int r = 0; r < 8; ++r) acc[r] = fmaf(a, hv[r], acc[r]);
  }
  const float di = dinv[(size_t)dst * nh + head];
  bf16x8 o;
#pragma unroll
  for (int r = 0; r < 8; ++r) {
    float v = acc[r] * di + bias[ch + r];
    v = v > 0.f ? v : (expf(v) - 1.0f);
    o[r] = (short)f2b_rne(v);
  }
  *(bf16x8*)(out + (size_t)dst * HC + ch) = o;
}

// ---------------- conv2 aggregate + ELU + mean-pool, fp8 gather, one block/graph ----------------
__global__ __launch_bounds__(256) void agg_pool(
    const unsigned char* __restrict__ h,
    const float* __restrict__ w_csr, const float* __restrict__ wself,
    const float* __restrict__ dinv,
    const int* __restrict__ rowptr, const int* __restrict__ csr_src,
    const float* __restrict__ bias, const int* __restrict__ grp,
    unsigned short* __restrict__ zb)
{
  const int g = blockIdx.x;
  const int wave = threadIdx.x >> 6;
  const int lane = threadIdx.x & 63;
  const int ch = lane << 3;
  const int head = lane >> 4;          // ch/128
  const int gbeg = grp[g], gend = grp[g + 1];
  float bch[8];
#pragma unroll
  for (int r = 0; r < 8; ++r) bch[r] = bias[ch + r];
  float pool[8] = {0.f, 0.f, 0.f, 0.f, 0.f, 0.f, 0.f, 0.f};
  float hv[8];

  for (int node = gbeg + wave; node < gend; node += 4) {
    const int beg = rowptr[node], end = rowptr[node + 1];
    float acc[8] = {0.f, 0.f, 0.f, 0.f, 0.f, 0.f, 0.f, 0.f};
    int e = beg;
    for (; e + 1 < end; e += 2) {
      int s0 = csr_src[e], s1 = csr_src[e + 1];
      float a0 = w_csr[(size_t)e * 4 + head];
      float a1 = w_csr[(size_t)(e + 1) * 4 + head];
      uint2 r0 = *(const uint2*)(h + (size_t)s0 * 512 + ch);
      uint2 r1 = *(const uint2*)(h + (size_t)s1 * 512 + ch);
      fp8x8_to_f32(r0, hv);
#pragma unroll
      for (int r = 0; r < 8; ++r) acc[r] = fmaf(a0, hv[r], acc[r]);
      fp8x8_to_f32(r1, hv);
#pragma unroll
      for (int r = 0; r < 8; ++r) acc[r] = fmaf(a1, hv[r], acc[r]);
    }
    if (e < end) {
      int s0 = csr_src[e];
      float a0 = w_csr[(size_t)e * 4 + head];
      uint2 r0 = *(const uint2*)(h + (size_t)s0 * 512 + ch);
      fp8x8_to_f32(r0, hv);
#pragma unroll
      for (int r = 0; r < 8; ++r) acc[r] = fmaf(a0, hv[r], acc[r]);
    }
    {
      float a = wself[(size_t)node * 4 + head];
      uint2 r0 = *(const uint2*)(h + (size_t)node * 512 + ch);
      fp8x8_to_f32(r0, hv);
#pragma unroll
      for (int r = 0; r < 8; ++r) acc[r] = fmaf(a, hv[r], acc[r]);
    }
    const float di = dinv[(size_t)node * 4 + head];
#pragma unroll
    for (int r = 0; r < 8; ++r) {
      float v = acc[r] * di + bch[r];
      v = v > 0.f ? v : (expf(v) - 1.0f);   // ELU
      pool[r] += v;
    }
  }

  __shared__ float red[4][512];
#pragma unroll
  for (int r = 0; r < 8; ++r) red[wave][ch + r] = pool[r];
  __syncthreads();
  const float inv = 1.0f / (float)max(gend - gbeg, 1);
#pragma unroll
  for (int k = 0; k < 2; ++k) {
    int c = threadIdx.x + k * 256;
    float s = (red[0][c] + red[1][c]) + (red[2][c] + red[3][c]);
    zb[(size_t)g * 576 + c] = f2b_rne(s * inv);
  }
}

// ---------------- launcher ----------------
extern "C" void kernel_launch(void* const* d_in, const int* in_sizes, int n_in,
                              void* d_out, int out_size, void* d_ws, size_t ws_size,
                              hipStream_t stream)
{
  const float* x      = (const float*)d_in[0];
  const int*   ei     = (const int*)d_in[1];
  const int*   batch  = (const int*)d_in[2];
  const float* fp     = (const float*)d_in[3];
  const float* W1     = (const float*)d_in[4];
  const float* a_src1 = (const float*)d_in[5];
  const float* a_dst1 = (const float*)d_in[6];
  const float* b1     = (const float*)d_in[7];
  const float* W2     = (const float*)d_in[8];
  const float* a_src2 = (const float*)d_in[9];
  const float* a_dst2 = (const float*)d_in[10];
  const float* b2     = (const float*)d_in[11];
  const float* Wfp    = (const float*)d_in[12];
  const float* bfp    = (const float*)d_in[13];
  const float* Wfc1   = (const float*)d_in[14];
  const float* bfc1   = (const float*)d_in[15];
  const float* Wfc2   = (const float*)d_in[16];
  const float* bfc2   = (const float*)d_in[17];
  float* out = (float*)d_out;

  const int NN = in_sizes[0] / 128;
  const int E  = in_sizes[1] / 2;
  const int G  = in_sizes[3] / 2048;
  const int FIN = 128, H = 4, C1 = 64, C2 = 128;
  const int HC1 = H * C1;   // 256
  const int HC2 = H * C2;   // 512
  const int KFP = in_sizes[3] / G;   // 2048
  const int KZ  = HC2 + 64;          // 576
  const int KS_FP = 16;
  const int KS_Z  = 9;

  // ---- workspace: liverange-overlaid regions ----
  char* base = (char*)d_ws;
  size_t off = 0;
  auto alloc = [&](size_t bytes) {
    char* p = base + off; off += (bytes + 255) & ~(size_t)255; return p;
  };
  // Region A: early xb(bf16)+h1b(fp8); late h2b(fp8)
  size_t xb_sz  = ((size_t)NN * FIN * 2 + 255) & ~(size_t)255;
  size_t h1b_sz = (size_t)NN * HC1;        // fp8: 1 B/elem
  size_t h2b_sz = (size_t)NN * HC2;        // fp8
  size_t rA = xb_sz + h1b_sz; if (h2b_sz > rA) rA = h2b_sz;
  char* RA = alloc(rA);
  unsigned short* xb  = (unsigned short*)RA;
  unsigned char*  h1b = (unsigned char*)(RA + xb_sz);
  unsigned char*  h2b = (unsigned char*)RA;
  // Region B: early fpb+Cp_fp; late agg1b (bf16 — GEMM input)
  size_t fpb_sz  = ((size_t)G * KFP * 2 + 255) & ~(size_t)255;
  size_t cpfp_sz = (size_t)KS_FP * G * 64 * 4;
  size_t agg1_sz = (size_t)NN * HC1 * 2;
  size_t rB = fpb_sz + cpfp_sz; if (agg1_sz > rB) rB = agg1_sz;
  char* RB = alloc(rB);
  unsigned short* fpb   = (unsigned short*)RB;
  float*          Cp_fp = (float*)(RB + fpb_sz);
  unsigned short* agg1b = (unsigned short*)RB;
  // Region C: attn buffers (conv1 then conv2 sequentially)
  float* w1     = (float*)alloc((size_t)E * H * 4);
  float* wself1 = (float*)alloc((size_t)NN * H * 4);
  float* es1    = (float*)alloc((size_t)NN * H * 4);
  float* ed1    = (float*)alloc((size_t)NN * H * 4);
  float* dinv1  = (float*)alloc((size_t)NN * H * 4);
  float* w2 = w1, *wself2 = wself1, *es2 = es1, *ed2 = ed1, *dinv2 = dinv1;
  // Persistent small buffers
  unsigned short* zb    = (unsigned short*)alloc((size_t)G * KZ * 2);
  float*          Cp_z  = (float*)alloc((size_t)KS_Z * G * 64 * 4);
  unsigned short* W1T   = (unsigned short*)alloc((size_t)HC1 * FIN * 2);
  unsigned short* W2T   = (unsigned short*)alloc((size_t)HC2 * HC1 * 2);
  unsigned short* WfpT  = (unsigned short*)alloc((size_t)64 * KFP * 2);
  unsigned short* Wfc1T = (unsigned short*)alloc((size_t)64 * KZ * 2);
  // int arena: deg/cursor/gcnt contiguous (single memset covers exactly this span)
  int* iarena   = (int*)alloc(((size_t)2 * NN + G) * 4);
  int* deg      = iarena;
  int* cursor   = iarena + NN;
  int* gcnt     = iarena + 2 * NN;
  int* rowptr_n = (int*)alloc(((size_t)NN + 1) * 4);
  int* rowptr_g = (int*)alloc(((size_t)G + 1) * 4);
  int* csr_src  = (int*)alloc((size_t)E * 4);
  int* bsumA    = (int*)alloc(128 * 4);
  int* bpreA    = (int*)alloc(128 * 4);
  int* bsumB    = (int*)alloc(128 * 4);
  int* bpreB    = (int*)alloc(128 * 4);

  // ---- fused prep ----
  const size_t nx = (size_t)NN * FIN;
  const size_t nf = (size_t)G * KFP;
  const int B0 = (int)((nx + 255) / 256);
  const int B1 = (int)((nf + 255) / 256);
  {
    int nb = B0 + B1 + 128 + 512 + 512 + 144;
    prep_all<<<nb, 256, 0, stream>>>(x, xb, nx, B0, fp, fpb, nf, B1,
                                     W1, W1T, W2, W2T, Wfp, WfpT, Wfc1, Wfc1T);
  }

  // ---- fingerprint branch ----
  {
    dim3 gg(KS_FP, G / 128);
    gemm_mfma_n64<<<gg, 256, 0, stream>>>(fpb, KFP, WfpT, KFP, Cp_fp, G, KFP / KS_FP);
    fp_finish<<<G, 64, 0, stream>>>(Cp_fp, KS_FP, G, bfp, zb);
  }

  // ---- CSR by dst + graph segment ptrs ----
  hipMemsetAsync(iarena, 0, sizeof(int) * ((size_t)2 * NN + G), stream);
  {
    int BE = (E + 255) / 256;
    int BN = (NN + 255) / 256;
    count_all<<<BE + BN, 256, 0, stream>>>(ei, E, deg, batch, NN, gcnt, BE);
  }
  {
    int nbA = (NN + 1023) / 1024;
    int nbB = (G + 1023) / 1024;
    scan2_p1<<<nbA + nbB, 256, 0, stream>>>(deg, NN, bsumA, nbA, gcnt, G, bsumB);
    scan2_p2<<<2, 128, 0, stream>>>(bsumA, bpreA, nbA, rowptr_n, NN,
                                    bsumB, bpreB, nbB, rowptr_g, G);
    scan2_p3<<<nbA + nbB, 256, 0, stream>>>(deg, bpreA, NN, rowptr_n, nbA,
                                            gcnt, bpreB, G, rowptr_g);
  }
  fill_csr<<<(E + 255) / 256, 256, 0, stream>>>(ei, E, cursor, rowptr_n, csr_src);

  // ---- conv1: GEMM (fp8 h1 + fused e) -> alpha -> aggregate ----
  {
    dim3 gg(HC1 / 128, (NN + 127) / 128);
    gemm_mfma<64><<<gg, 256, 0, stream>>>(xb, W1T, h1b, NN, HC1, FIN,
                                          a_src1, a_dst1, es1, ed1, H);
  }
  alpha_kernel<<<(NN * H + 255) / 256, 256, 0, stream>>>(es1, ed1, rowptr_n, csr_src,
                                                         w1, wself1, dinv1, NN, H);
  aggregate_b<<<(NN + 7) / 8, 256, 0, stream>>>(h1b, w1, wself1, dinv1, rowptr_n, csr_src,
                                                b1, agg1b, NN, H, C1);

  // ---- conv2: GEMM (fp8 h2 + fused e) -> alpha -> fused aggregate+pool ----
  {
    dim3 gg(HC2 / 128, (NN + 127) / 128);
    gemm_mfma<128><<<gg, 256, 0, stream>>>(agg1b, W2T, h2b, NN, HC2, HC1,
                                           a_src2, a_dst2, es2, ed2, H);
  }
  alpha_kernel<<<(NN * H + 255) / 256, 256, 0, stream>>>(es2, ed2, rowptr_n, csr_src,
                                                         w2, wself2, dinv2, NN, H);
  agg_pool<<<G, 256, 0, stream>>>(h2b, w2, wself2, dinv2, rowptr_n, csr_src,
                                  b2, rowptr_g, zb);

  // ---- head ----
  {
    dim3 gg(KS_Z, G / 128);
    gemm_mfma_n64<<<gg, 256, 0, stream>>>(zb, KZ, Wfc1T, KZ, Cp_z, G, KZ / KS_Z);
    mlp_finish<<<G, 64, 0, stream>>>(Cp_z, KS_Z, G, bfc1, Wfc2, bfc2, out);
  }
}